// Round 1
// baseline (585.386 us; speedup 1.0000x reference)
//
#include <hip/hip_runtime.h>
#include <hip/hip_bf16.h>
#include <math.h>

#define Bk 8
#define Nk 10000
#define Hk 64
#define Lk 4
#define Rk 3
#define Ek 200000
#define FPk 2048

#define CNTB ((Rk*Ek + 255)/256)   /* 2344 count/fill blocks */
#define INITB 2048

typedef unsigned short u16;
typedef unsigned int   u32;
typedef _Float16 f16;
typedef __attribute__((ext_vector_type(2))) _Float16 f16x2;
typedef __attribute__((ext_vector_type(8))) _Float16 f16x8;
typedef __attribute__((ext_vector_type(4))) float f32x4;

__device__ __forceinline__ f16x2 as_h2(u32 u){
    union{u32 i; f16x2 h;} v; v.i = u; return v.h;
}
__device__ __forceinline__ u32 as_u32(f16x2 h){
    union{u32 i; f16x2 h;} v; v.h = h; return v.i;
}
__device__ __forceinline__ u16 f2h_bits(float f){
    union{f16 h; u16 u;} v; v.h = (f16)f; return v.u;
}

// ---------------------------------------------------------------------------
// Weight prep (fp16, MFMA B layout) + deg zeroing. Grid covers 65536 threads.
// ---------------------------------------------------------------------------
__global__ void k_wprep(const float* __restrict__ Wself, const float* __restrict__ Wrel,
                        u16* __restrict__ wt, int* __restrict__ deg){
    int idx = blockIdx.x*256 + threadIdx.x;
    if(idx < Rk*Nk) deg[idx] = 0;
    if(idx >= Lk*4*2*4*64*8) return;
    int j    = idx & 7;
    int lane = (idx >> 3) & 63;
    int jt   = (idx >> 9) & 3;
    int kc   = (idx >> 11) & 1;
    int mt   = (idx >> 12) & 3;
    int l    = idx >> 14;
    int k    = kc*32 + (lane >> 4)*8 + j;
    int col  = jt*16 + (lane & 15);
    float w = (mt == 0) ? Wself[(l*64 + k)*64 + col]
                        : Wrel[((l*3 + (mt-1))*64 + k)*64 + col];
    wt[idx] = f2h_bits(w);
}

// ---------------------------------------------------------------------------
// Fused: deg count (blocks < CNTB) + FiLM stage 1 (512 blocks after)
// ---------------------------------------------------------------------------
__global__ void k_count_film1(const int* __restrict__ edge_index, int* __restrict__ deg,
                              const float* __restrict__ fp, const float* __restrict__ W1,
                              const float* __restrict__ b1, float* __restrict__ hid){
    __shared__ float red[256];
    if(blockIdx.x < CNTB){
        int idx = blockIdx.x*256 + threadIdx.x;
        if(idx >= Rk*Ek) return;
        int r = idx / Ek, e = idx % Ek;
        int dst = edge_index[r*2*Ek + Ek + e];
        atomicAdd(&deg[r*Nk + dst], 1);
    }else{
        int bb = blockIdx.x - CNTB;            // 0..511
        int b = bb >> 6, h = bb & 63;
        const float* fpb = fp + b*FPk;
        float acc = 0.f;
        for(int k = threadIdx.x; k < FPk; k += 256)
            acc += fpb[k] * W1[k*64 + h];
        red[threadIdx.x] = acc;
        __syncthreads();
        for(int s = 128; s >= 1; s >>= 1){
            if(threadIdx.x < s) red[threadIdx.x] += red[threadIdx.x + s];
            __syncthreads();
        }
        if(threadIdx.x == 0) hid[b*64 + h] = fmaxf(red[0] + b1[h], 0.f);
    }
}

// ---------------------------------------------------------------------------
// Fused: CSR scan (blocks 0..2, 1024 thr) + FiLM stage 2 (blocks 3..10)
// ---------------------------------------------------------------------------
__global__ void k_scan_film2(const int* __restrict__ deg, int* __restrict__ offs,
                             int* __restrict__ cursor,
                             const float* __restrict__ hid, const float* __restrict__ W2,
                             const float* __restrict__ b2,
                             float* __restrict__ g1p, float* __restrict__ beta){
    __shared__ int s[1024];
    if(blockIdx.x < 3){
        int r = blockIdx.x;
        int t = threadIdx.x;
        int base_i = t*10;
        int local[10];
        int sum = 0;
        if(base_i < Nk){
            #pragma unroll
            for(int k = 0; k < 10; ++k){ local[k] = deg[r*Nk + base_i + k]; sum += local[k]; }
        }
        s[t] = sum;
        __syncthreads();
        for(int d = 1; d < 1024; d <<= 1){
            int v = (t >= d) ? s[t-d] : 0;
            __syncthreads();
            s[t] += v;
            __syncthreads();
        }
        if(base_i < Nk){
            int excl = s[t] - sum;
            #pragma unroll
            for(int k = 0; k < 10; ++k){
                offs[r*(Nk+1) + base_i + k] = excl;
                cursor[r*Nk + base_i + k]   = excl;
                excl += local[k];
            }
        }
        if(t == 1023) offs[r*(Nk+1) + Nk] = s[1023];
    }else{
        int b = blockIdx.x - 3;                // 0..7
        int j = threadIdx.x;
        if(j < 128){
            float acc = b2[j];
            for(int k = 0; k < 64; ++k)
                acc += hid[b*64 + k] * W2[k*128 + j];
            if(j < 64) g1p[b*64 + j] = 1.f + tanhf(acc);
            else       beta[b*64 + j - 64] = acc;
        }
    }
}

// ---------------------------------------------------------------------------
// Fused: CSR fill (blocks < CNTB) + x0 init (INITB blocks after)
// ---------------------------------------------------------------------------
__global__ void k_fill_init(const int* __restrict__ edge_index, const float* __restrict__ edge_weight,
                            int* __restrict__ cursor, int2* __restrict__ epack,
                            const float* __restrict__ ctl, const float* __restrict__ dt,
                            const int* __restrict__ cell_idx,
                            const float* __restrict__ W_se, const float* __restrict__ b_se,
                            const float* __restrict__ cell_emb,
                            const float* __restrict__ g1p, const float* __restrict__ beta,
                            u16* __restrict__ xh){
    if(blockIdx.x < CNTB){
        int idx = blockIdx.x*256 + threadIdx.x;
        if(idx >= Rk*Ek) return;
        int r = idx / Ek, e = idx % Ek;
        int src = edge_index[r*2*Ek + e];
        int dst = edge_index[r*2*Ek + Ek + e];
        int pos = atomicAdd(&cursor[r*Nk + dst], 1);
        f16 h = (f16)edge_weight[r*Ek + e];
        epack[(size_t)r*Ek + pos] = make_int2(src << 7, (int)as_u32((f16x2){h, h}));
    }else{
        const size_t total = (size_t)Bk*Nk*64;
        size_t start = (size_t)(blockIdx.x - CNTB)*256 + threadIdx.x;
        for(size_t i = start; i < total; i += (size_t)INITB*256){
            int h = (int)(i & 63);
            size_t bn = i >> 6;
            int b = (int)(bn / Nk);
            float w = W_se[h], bs = b_se[h];
            float v = fmaxf(ctl[bn]*w + bs, 0.f) + fmaxf(dt[bn]*w + bs, 0.f)
                    + cell_emb[cell_idx[b]*64 + h];
            xh[i] = f2h_bits(v * g1p[b*64 + h] + beta[b*64 + h]);
        }
    }
}

// ---------------------------------------------------------------------------
// FUSED layer: gather (k_agg structure) + MFMA proj + LN + ReLU (+ readout).
// Wave = 16 output nodes of ONE batch. The wave gathers agg[r][its 16 nodes]
// for all 3 relations into its private LDS tile (padded stride 36 dwords,
// 2-way-max bank aliasing = free), then runs the 4-matrix MFMA on them.
// Producer == consumer wave -> NO barrier anywhere; waves fully independent.
// b = blockIdx&7 pins each batch to one XCD: x_in (1.28MB) + x_out (1.28MB)
// slices stay L2-resident per XCD, across all 4 layers (ping-pong buffers).
// Gather inner loop is the R11-proven k_agg body (int4 stash, 8 gathers in
// flight, 256B/instr); halves split edge ranges instead of batches.
// Eliminates the aggh 30MB HBM write + 30MB read per layer and 4 launches.
// ---------------------------------------------------------------------------
__global__ __launch_bounds__(256) void k_layer(
        const u16* __restrict__ xin, u16* __restrict__ xout,
        const int* __restrict__ offs, const int2* __restrict__ epack,
        const u16* __restrict__ wt,
        const float* __restrict__ ln_g, const float* __restrict__ ln_b, int l,
        int last, const float* __restrict__ W_out, const float* __restrict__ b_out,
        float* __restrict__ out){
    __shared__ u32  aggl[4][3*16*36];      // per-wave agg tiles, 27.6KB
    __shared__ int2 stash[4][64];          // per-wave edge stash, 2KB

    int b    = blockIdx.x & 7;             // batch == XCD slice
    int tile = blockIdx.x >> 3;            // 0..156
    int wq   = threadIdx.x >> 6;
    int lane = threadIdx.x & 63;
    int n0   = tile*64 + wq*16;            // this wave's 16 nodes
    if(n0 >= Nk) return;                   // no barriers -> safe early exit

    int fg   = lane & 31;                  // feat dword (2 feats)
    int half = lane >> 5;                  // edge-range half
    u32*  ag = aggl[wq];
    int2* st = stash[wq];

    // ---- gather phase: 48 (r,node) pairs, all consumed by this wave ----
    {
        const char* xb = (const char*)xin + (size_t)b*Nk*128 + fg*4;
        for(int p = 0; p < 48; ++p){
            int r    = p >> 4;
            int node = n0 + (p & 15);
            int o0 = offs[r*(Nk+1) + node];
            int o1 = offs[r*(Nk+1) + node + 1];
            const int2* ep = epack + (size_t)r*Ek;
            f16x2 A = (f16x2){0,0}, C = (f16x2){0,0};
            for(int base = o0; base < o1; base += 64){
                int j = base + lane;
                if(j < o1) st[lane] = ep[j];
                int cnt = min(o1 - base, 64);
                int t = 0;
                for(; t + 16 <= cnt; t += 16){
                    int b0 = t + half*8;            // halves take disjoint 8-edge runs
                    int4 q01 = *(const int4*)&st[b0];
                    int4 q23 = *(const int4*)&st[b0+2];
                    int4 q45 = *(const int4*)&st[b0+4];
                    int4 q67 = *(const int4*)&st[b0+6];
                    u32 u0 = *(const u32*)(xb + q01.x);
                    u32 u1 = *(const u32*)(xb + q01.z);
                    u32 u2 = *(const u32*)(xb + q23.x);
                    u32 u3 = *(const u32*)(xb + q23.z);
                    u32 u4 = *(const u32*)(xb + q45.x);
                    u32 u5 = *(const u32*)(xb + q45.z);
                    u32 u6 = *(const u32*)(xb + q67.x);
                    u32 u7 = *(const u32*)(xb + q67.z);
                    A += as_h2(u0)*as_h2(q01.y); C += as_h2(u1)*as_h2(q01.w);
                    A += as_h2(u2)*as_h2(q23.y); C += as_h2(u3)*as_h2(q23.w);
                    A += as_h2(u4)*as_h2(q45.y); C += as_h2(u5)*as_h2(q45.w);
                    A += as_h2(u6)*as_h2(q67.y); C += as_h2(u7)*as_h2(q67.w);
                }
                for(; t + 4 <= cnt; t += 4){        // halves take 2 edges each
                    int4 q = *(const int4*)&st[t + half*2];
                    u32 u0 = *(const u32*)(xb + q.x);
                    u32 u1 = *(const u32*)(xb + q.z);
                    A += as_h2(u0)*as_h2(q.y); C += as_h2(u1)*as_h2(q.w);
                }
                if(half == 0){                      // <=3 leftover edges
                    for(; t < cnt; ++t){
                        int2 q = st[t];
                        u32 u = *(const u32*)(xb + q.x);
                        A += as_h2(u)*as_h2(q.y);
                    }
                }
            }
            float a0 = (float)A.x + (float)C.x;
            float a1 = (float)A.y + (float)C.y;
            a0 += __shfl_xor(a0, 32);
            a1 += __shfl_xor(a1, 32);
            if(half == 0)
                ag[p*36 + fg] = (u32)f2h_bits(a0) | ((u32)f2h_bits(a1) << 16);
        }
    }

    // ---- MFMA phase: 16 nodes x 64 feats, A from global x (mt=0) + LDS agg ----
    int mrow = lane & 15;
    int kq   = lane >> 4;
    f32x4 acc[4];
    #pragma unroll
    for(int jt = 0; jt < 4; ++jt) acc[jt] = (f32x4){0.f,0.f,0.f,0.f};

    const u16* wl   = wt + (size_t)l*16384;
    const u16* arow = xin + ((size_t)b*Nk + n0 + mrow)*64;

    #pragma unroll
    for(int kc = 0; kc < 2; ++kc){
        f16x8 aA = *(const f16x8*)(arow + kc*32 + kq*8);
        #pragma unroll
        for(int jt = 0; jt < 4; ++jt){
            f16x8 bfrag = *(const f16x8*)(wl + ((size_t)(kc*4 + jt)*64 + lane)*8);
            acc[jt] = __builtin_amdgcn_mfma_f32_16x16x32_f16(aA, bfrag, acc[jt], 0, 0, 0);
        }
    }
    #pragma unroll
    for(int mt = 1; mt < 4; ++mt){
        #pragma unroll
        for(int kc = 0; kc < 2; ++kc){
            f16x8 aA = *(const f16x8*)&ag[((mt-1)*16 + mrow)*36 + kc*16 + kq*4];
            #pragma unroll
            for(int jt = 0; jt < 4; ++jt){
                f16x8 bfrag = *(const f16x8*)(wl + ((size_t)((mt*2 + kc)*4 + jt)*64 + lane)*8);
                acc[jt] = __builtin_amdgcn_mfma_f32_16x16x32_f16(aA, bfrag, acc[jt], 0, 0, 0);
            }
        }
    }

    // ---- LN + ReLU epilogue (feature dim = mrow x jt), fused readout on last ----
    float gv[4], bv[4], wo[4];
    #pragma unroll
    for(int jt = 0; jt < 4; ++jt){
        int f = jt*16 + mrow;
        gv[jt] = ln_g[l*64 + f];
        bv[jt] = ln_b[l*64 + f];
        wo[jt] = W_out[f];
    }
    float bo = b_out[0];
    u16* xdst = xout + (size_t)b*Nk*64;

    #pragma unroll
    for(int v = 0; v < 4; ++v){
        float s1 = acc[0][v] + acc[1][v] + acc[2][v] + acc[3][v];
        float s2 = acc[0][v]*acc[0][v] + acc[1][v]*acc[1][v]
                 + acc[2][v]*acc[2][v] + acc[3][v]*acc[3][v];
        #pragma unroll
        for(int off = 1; off <= 8; off <<= 1){
            s1 += __shfl_xor(s1, off);
            s2 += __shfl_xor(s2, off);
        }
        float mu  = s1 * 0.015625f;
        float var = s2 * 0.015625f - mu*mu;
        float rstd = rsqrtf(var + 1e-3f);
        int node = n0 + kq*4 + v;
        if(!last){
            #pragma unroll
            for(int jt = 0; jt < 4; ++jt){
                float o = (acc[jt][v] - mu) * rstd * gv[jt] + bv[jt];
                xdst[(size_t)node*64 + jt*16 + mrow] = f2h_bits(fmaxf(o, 0.f));
            }
        }else{
            float s3 = 0.f;
            #pragma unroll
            for(int jt = 0; jt < 4; ++jt){
                float o = (acc[jt][v] - mu) * rstd * gv[jt] + bv[jt];
                s3 += fmaxf(o, 0.f) * wo[jt];
            }
            #pragma unroll
            for(int off = 1; off <= 8; off <<= 1)
                s3 += __shfl_xor(s3, off);
            if(mrow == 0)
                out[(size_t)b*Nk + node] = s3 + bo;
        }
    }
}

// ---------------------------------------------------------------------------
extern "C" void kernel_launch(void* const* d_in, const int* in_sizes, int n_in,
                              void* d_out, int out_size, void* d_ws, size_t ws_size,
                              hipStream_t stream){
    const float* ctl        = (const float*)d_in[0];
    const float* dt         = (const float*)d_in[1];
    const float* drug_fp    = (const float*)d_in[2];
    const float* edge_w     = (const float*)d_in[3];
    const int*   cell_idx   = (const int*)  d_in[4];
    const int*   edge_index = (const int*)  d_in[5];
    const float* W_se       = (const float*)d_in[6];
    const float* b_se       = (const float*)d_in[7];
    const float* cell_emb   = (const float*)d_in[8];
    const float* W_f1       = (const float*)d_in[9];
    const float* b_f1       = (const float*)d_in[10];
    const float* W_f2       = (const float*)d_in[11];
    const float* b_f2       = (const float*)d_in[12];
    const float* Wself      = (const float*)d_in[13];
    const float* Wrel       = (const float*)d_in[14];
    const float* ln_g       = (const float*)d_in[15];
    const float* ln_b       = (const float*)d_in[16];
    const float* W_out      = (const float*)d_in[17];
    const float* b_out      = (const float*)d_in[18];
    float* out = (float*)d_out;

    char* p = (char*)d_ws;
    auto alloc = [&](size_t bytes)->char*{
        char* r = p; p += (bytes + 255) & ~(size_t)255; return r;
    };
    int*   deg    = (int*)  alloc((size_t)Rk*Nk*4);
    int*   cursor = (int*)  alloc((size_t)Rk*Nk*4);
    int*   offs   = (int*)  alloc((size_t)Rk*(Nk+1)*4);
    int2*  epack  = (int2*) alloc((size_t)Rk*Ek*8);
    float* hid    = (float*)alloc((size_t)Bk*64*4);
    float* g1p    = (float*)alloc((size_t)Bk*64*4);
    float* beta   = (float*)alloc((size_t)Bk*64*4);
    u16*   xh0    = (u16*)  alloc((size_t)Bk*Nk*64*2);
    u16*   xh1    = (u16*)  alloc((size_t)Bk*Nk*64*2);
    u16*   wt     = (u16*)  alloc((size_t)Lk*16384*2);

    // weight prep + deg zeroing (65536 threads covers wt AND deg)
    k_wprep<<<(Lk*4*2*4*64*8 + 255)/256, 256, 0, stream>>>(Wself, Wrel, wt, deg);

    // fused prep pipeline
    k_count_film1<<<CNTB + Bk*64, 256, 0, stream>>>(edge_index, deg, drug_fp, W_f1, b_f1, hid);
    k_scan_film2<<<3 + Bk, 1024, 0, stream>>>(deg, offs, cursor, hid, W_f2, b_f2, g1p, beta);
    k_fill_init<<<CNTB + INITB, 256, 0, stream>>>(edge_index, edge_w, cursor, epack,
                                                  ctl, dt, cell_idx, W_se, b_se, cell_emb,
                                                  g1p, beta, xh0);

    // fused layers: one kernel each, ping-pong x buffers
    const int ntile = (Nk + 63)/64;            // 157
    for(int l = 0; l < Lk; ++l){
        u16* xin  = (l & 1) ? xh1 : xh0;
        u16* xout = (l & 1) ? xh0 : xh1;
        k_layer<<<ntile*8, 256, 0, stream>>>(
            xin, xout, offs, epack, wt, ln_g, ln_b, l,
            (l == Lk-1) ? 1 : 0, W_out, b_out, out);
    }
}

// Round 2
// 412.910 us; speedup vs baseline: 1.4177x; 1.4177x over previous
//
#include <hip/hip_runtime.h>
#include <hip/hip_bf16.h>
#include <math.h>

#define Bk 8
#define Nk 10000
#define Hk 64
#define Lk 4
#define Rk 3
#define Ek 200000
#define FPk 2048

#define C4 (Rk*Ek/4)              /* 150000 edge-quads */
#define CNT4B ((C4 + 255)/256)    /* 586 count/fill blocks (4 edges/thread) */
#define INITB 2048

typedef unsigned short u16;
typedef unsigned int   u32;
typedef _Float16 f16;
typedef __attribute__((ext_vector_type(2))) _Float16 f16x2;
typedef __attribute__((ext_vector_type(8))) _Float16 f16x8;
typedef __attribute__((ext_vector_type(4))) float f32x4;

__device__ __forceinline__ f16x2 as_h2(u32 u){
    union{u32 i; f16x2 h;} v; v.i = u; return v.h;
}
__device__ __forceinline__ u32 as_u32(f16x2 h){
    union{u32 i; f16x2 h;} v; v.h = h; return v.i;
}
__device__ __forceinline__ u16 f2h_bits(float f){
    union{f16 h; u16 u;} v; v.h = (f16)f; return v.u;
}

// ---------------------------------------------------------------------------
// Weight prep (fp16, MFMA B layout) + deg zeroing. Grid covers 65536 threads.
// ---------------------------------------------------------------------------
__global__ void k_wprep(const float* __restrict__ Wself, const float* __restrict__ Wrel,
                        u16* __restrict__ wt, int* __restrict__ deg){
    int idx = blockIdx.x*256 + threadIdx.x;
    if(idx < Rk*Nk) deg[idx] = 0;
    if(idx >= Lk*4*2*4*64*8) return;
    int j    = idx & 7;
    int lane = (idx >> 3) & 63;
    int jt   = (idx >> 9) & 3;
    int kc   = (idx >> 11) & 1;
    int mt   = (idx >> 12) & 3;
    int l    = idx >> 14;
    int k    = kc*32 + (lane >> 4)*8 + j;
    int col  = jt*16 + (lane & 15);
    float w = (mt == 0) ? Wself[(l*64 + k)*64 + col]
                        : Wrel[((l*3 + (mt-1))*64 + k)*64 + col];
    wt[idx] = f2h_bits(w);
}

// ---------------------------------------------------------------------------
// Fused: deg count (blocks < CNT4B, 4 edges/thread via int4) + FiLM stage 1
// ---------------------------------------------------------------------------
__global__ void k_count_film1(const int* __restrict__ edge_index, int* __restrict__ deg,
                              const float* __restrict__ fp, const float* __restrict__ W1,
                              const float* __restrict__ b1, float* __restrict__ hid){
    __shared__ float red[256];
    if(blockIdx.x < CNT4B){
        int idx = blockIdx.x*256 + threadIdx.x;
        if(idx >= C4) return;
        int g = idx*4;
        int r = g / Ek, e = g % Ek;          // Ek%4==0 -> quad shares r
        int4 d = *(const int4*)&edge_index[r*2*Ek + Ek + e];
        int* dg = deg + r*Nk;
        atomicAdd(&dg[d.x], 1);
        atomicAdd(&dg[d.y], 1);
        atomicAdd(&dg[d.z], 1);
        atomicAdd(&dg[d.w], 1);
    }else{
        int bb = blockIdx.x - CNT4B;         // 0..511
        int b = bb >> 6, h = bb & 63;
        const float* fpb = fp + b*FPk;
        float acc = 0.f;
        for(int k = threadIdx.x; k < FPk; k += 256)
            acc += fpb[k] * W1[k*64 + h];
        red[threadIdx.x] = acc;
        __syncthreads();
        for(int s = 128; s >= 1; s >>= 1){
            if(threadIdx.x < s) red[threadIdx.x] += red[threadIdx.x + s];
            __syncthreads();
        }
        if(threadIdx.x == 0) hid[b*64 + h] = fmaxf(red[0] + b1[h], 0.f);
    }
}

// ---------------------------------------------------------------------------
// Fused: CSR scan (blocks 0..2, 1024 thr) + FiLM stage 2 (blocks 3..10)
// ---------------------------------------------------------------------------
__global__ void k_scan_film2(const int* __restrict__ deg, int* __restrict__ offs,
                             int* __restrict__ cursor,
                             const float* __restrict__ hid, const float* __restrict__ W2,
                             const float* __restrict__ b2,
                             float* __restrict__ g1p, float* __restrict__ beta){
    __shared__ int s[1024];
    if(blockIdx.x < 3){
        int r = blockIdx.x;
        int t = threadIdx.x;
        int base_i = t*10;
        int local[10];
        int sum = 0;
        if(base_i < Nk){
            #pragma unroll
            for(int k = 0; k < 10; ++k){ local[k] = deg[r*Nk + base_i + k]; sum += local[k]; }
        }
        s[t] = sum;
        __syncthreads();
        for(int d = 1; d < 1024; d <<= 1){
            int v = (t >= d) ? s[t-d] : 0;
            __syncthreads();
            s[t] += v;
            __syncthreads();
        }
        if(base_i < Nk){
            int excl = s[t] - sum;
            #pragma unroll
            for(int k = 0; k < 10; ++k){
                offs[r*(Nk+1) + base_i + k] = excl;
                cursor[r*Nk + base_i + k]   = excl;
                excl += local[k];
            }
        }
        if(t == 1023) offs[r*(Nk+1) + Nk] = s[1023];
    }else{
        int b = blockIdx.x - 3;                // 0..7
        int j = threadIdx.x;
        if(j < 128){
            float acc = b2[j];
            for(int k = 0; k < 64; ++k)
                acc += hid[b*64 + k] * W2[k*128 + j];
            if(j < 64) g1p[b*64 + j] = 1.f + tanhf(acc);
            else       beta[b*64 + j - 64] = acc;
        }
    }
}

// ---------------------------------------------------------------------------
// Fused: CSR fill (blocks < CNT4B, 4 edges/thread) + x0 init (8 feats/thread,
// 16B stores) on INITB blocks after.
// ---------------------------------------------------------------------------
__global__ void k_fill_init(const int* __restrict__ edge_index, const float* __restrict__ edge_weight,
                            int* __restrict__ cursor, int2* __restrict__ epack,
                            const float* __restrict__ ctl, const float* __restrict__ dt,
                            const int* __restrict__ cell_idx,
                            const float* __restrict__ W_se, const float* __restrict__ b_se,
                            const float* __restrict__ cell_emb,
                            const float* __restrict__ g1p, const float* __restrict__ beta,
                            u16* __restrict__ xh){
    if(blockIdx.x < CNT4B){
        int idx = blockIdx.x*256 + threadIdx.x;
        if(idx >= C4) return;
        int g = idx*4;
        int r = g / Ek, e = g % Ek;
        int4   s4 = *(const int4*)  &edge_index [r*2*Ek + e];
        int4   d4 = *(const int4*)  &edge_index [r*2*Ek + Ek + e];
        float4 w4 = *(const float4*)&edge_weight[r*Ek + e];
        int2* epr = epack + (size_t)r*Ek;
        int*  cur = cursor + r*Nk;
        int pos;
        f16 h;
        pos = atomicAdd(&cur[d4.x], 1); h = (f16)w4.x;
        epr[pos] = make_int2(s4.x << 7, (int)as_u32((f16x2){h, h}));
        pos = atomicAdd(&cur[d4.y], 1); h = (f16)w4.y;
        epr[pos] = make_int2(s4.y << 7, (int)as_u32((f16x2){h, h}));
        pos = atomicAdd(&cur[d4.z], 1); h = (f16)w4.z;
        epr[pos] = make_int2(s4.z << 7, (int)as_u32((f16x2){h, h}));
        pos = atomicAdd(&cur[d4.w], 1); h = (f16)w4.w;
        epr[pos] = make_int2(s4.w << 7, (int)as_u32((f16x2){h, h}));
    }else{
        const size_t total8 = (size_t)Bk*Nk*8;       // 640000 feat-octets
        size_t start = (size_t)(blockIdx.x - CNT4B)*256 + threadIdx.x;
        for(size_t i8 = start; i8 < total8; i8 += (size_t)INITB*256){
            int hq = (int)(i8 & 7);                  // feat octet 0..7
            size_t bn = i8 >> 3;
            int b = (int)(bn / Nk);
            float c = ctl[bn], d = dt[bn];
            int ci = cell_idx[b];
            u32 pk[4];
            #pragma unroll
            for(int j = 0; j < 8; j += 2){
                int h0 = hq*8 + j, h1 = h0 + 1;
                float w0 = W_se[h0], s0 = b_se[h0];
                float w1 = W_se[h1], s1 = b_se[h1];
                float v0 = fmaxf(c*w0 + s0, 0.f) + fmaxf(d*w0 + s0, 0.f)
                         + cell_emb[ci*64 + h0];
                float v1 = fmaxf(c*w1 + s1, 0.f) + fmaxf(d*w1 + s1, 0.f)
                         + cell_emb[ci*64 + h1];
                v0 = v0 * g1p[b*64 + h0] + beta[b*64 + h0];
                v1 = v1 * g1p[b*64 + h1] + beta[b*64 + h1];
                pk[j >> 1] = (u32)f2h_bits(v0) | ((u32)f2h_bits(v1) << 16);
            }
            *(int4*)&xh[i8*8] = make_int4(pk[0], pk[1], pk[2], pk[3]);
        }
    }
}

// ---------------------------------------------------------------------------
// agg (fp16): wave = one (r,dst) x 2 batches (lane>>5) x 32 feat-dwords (lane&31).
// R11-proven structure (120k waves, LDS stash, pk_fma), deepened: 16 gathers
// in flight per step (was 8) to test whether the ~12.7 TB/s plateau is
// CU-latency-bound rather than L2-bound. Request-rate arithmetic: 0.165
// vmem/cy/CU at 47.4us leaves large issue headroom.
// bpair=blockIdx&3 -> per-XCD 2.56MB x-slice (L2-hit).
// ---------------------------------------------------------------------------
__global__ __launch_bounds__(256) void k_agg(const u16* __restrict__ xh,
                      const int* __restrict__ offs, const int2* __restrict__ epack,
                      u16* __restrict__ aggh){
    __shared__ int2 stash[4][64];
    int bpair = blockIdx.x & 3;
    int grp   = blockIdx.x >> 2;                   // 0..7499
    int wq    = threadIdx.x >> 6;
    int wid   = grp*4 + wq;                        // 0..29999 = (r,dst)
    int lane  = threadIdx.x & 63;
    int fg    = lane & 31;                         // feat dword: feats fg*2, fg*2+1
    int bl    = lane >> 5;                         // local batch 0/1
    int b     = bpair*2 + bl;
    int r = wid / Nk, dst = wid % Nk;
    int o0 = offs[r*(Nk+1) + dst], o1 = offs[r*(Nk+1) + dst + 1];
    const int2* ep = epack + (size_t)r*Ek;
    const char* xb = (const char*)xh + (size_t)b*Nk*128 + fg*4;

    f16x2 A = (f16x2){0,0}, C = (f16x2){0,0};      // 2 accumulation chains
    int2* st = stash[wq];
    for(int base = o0; base < o1; base += 64){
        int j = base + lane;
        if(j < o1) st[lane] = ep[j];
        int cnt = min(o1 - base, 64);
        int t = 0;
        for(; t + 16 <= cnt; t += 16){
            int4 q0 = *(const int4*)&st[t];
            int4 q1 = *(const int4*)&st[t+2];
            int4 q2 = *(const int4*)&st[t+4];
            int4 q3 = *(const int4*)&st[t+6];
            int4 q4 = *(const int4*)&st[t+8];
            int4 q5 = *(const int4*)&st[t+10];
            int4 q6 = *(const int4*)&st[t+12];
            int4 q7 = *(const int4*)&st[t+14];
            u32 u0 = *(const u32*)(xb + q0.x);
            u32 u1 = *(const u32*)(xb + q0.z);
            u32 u2 = *(const u32*)(xb + q1.x);
            u32 u3 = *(const u32*)(xb + q1.z);
            u32 u4 = *(const u32*)(xb + q2.x);
            u32 u5 = *(const u32*)(xb + q2.z);
            u32 u6 = *(const u32*)(xb + q3.x);
            u32 u7 = *(const u32*)(xb + q3.z);
            u32 u8 = *(const u32*)(xb + q4.x);
            u32 u9 = *(const u32*)(xb + q4.z);
            u32 ua = *(const u32*)(xb + q5.x);
            u32 ub = *(const u32*)(xb + q5.z);
            u32 uc = *(const u32*)(xb + q6.x);
            u32 ud = *(const u32*)(xb + q6.z);
            u32 ue = *(const u32*)(xb + q7.x);
            u32 uf = *(const u32*)(xb + q7.z);
            A += as_h2(u0)*as_h2(q0.y); C += as_h2(u1)*as_h2(q0.w);
            A += as_h2(u2)*as_h2(q1.y); C += as_h2(u3)*as_h2(q1.w);
            A += as_h2(u4)*as_h2(q2.y); C += as_h2(u5)*as_h2(q2.w);
            A += as_h2(u6)*as_h2(q3.y); C += as_h2(u7)*as_h2(q3.w);
            A += as_h2(u8)*as_h2(q4.y); C += as_h2(u9)*as_h2(q4.w);
            A += as_h2(ua)*as_h2(q5.y); C += as_h2(ub)*as_h2(q5.w);
            A += as_h2(uc)*as_h2(q6.y); C += as_h2(ud)*as_h2(q6.w);
            A += as_h2(ue)*as_h2(q7.y); C += as_h2(uf)*as_h2(q7.w);
        }
        for(; t + 8 <= cnt; t += 8){
            int4 q01 = *(const int4*)&st[t];
            int4 q23 = *(const int4*)&st[t+2];
            int4 q45 = *(const int4*)&st[t+4];
            int4 q67 = *(const int4*)&st[t+6];
            u32 u0 = *(const u32*)(xb + q01.x);
            u32 u1 = *(const u32*)(xb + q01.z);
            u32 u2 = *(const u32*)(xb + q23.x);
            u32 u3 = *(const u32*)(xb + q23.z);
            u32 u4 = *(const u32*)(xb + q45.x);
            u32 u5 = *(const u32*)(xb + q45.z);
            u32 u6 = *(const u32*)(xb + q67.x);
            u32 u7 = *(const u32*)(xb + q67.z);
            A += as_h2(u0)*as_h2(q01.y); C += as_h2(u1)*as_h2(q01.w);
            A += as_h2(u2)*as_h2(q23.y); C += as_h2(u3)*as_h2(q23.w);
            A += as_h2(u4)*as_h2(q45.y); C += as_h2(u5)*as_h2(q45.w);
            A += as_h2(u6)*as_h2(q67.y); C += as_h2(u7)*as_h2(q67.w);
        }
        for(; t + 2 <= cnt; t += 2){
            int4 q01 = *(const int4*)&st[t];
            u32 u0 = *(const u32*)(xb + q01.x);
            u32 u1 = *(const u32*)(xb + q01.z);
            A += as_h2(u0)*as_h2(q01.y); C += as_h2(u1)*as_h2(q01.w);
        }
        if(t < cnt){
            int2 p = st[t];
            u32 u = *(const u32*)(xb + p.x);
            A += as_h2(u)*as_h2(p.y);
        }
    }
    float a0 = (float)A.x + (float)C.x;
    float a1 = (float)A.y + (float)C.y;
    u32 packed = (u32)f2h_bits(a0) | ((u32)f2h_bits(a1) << 16);
    ((u32*)aggh)[(((size_t)r*Bk + b)*Nk + dst)*32 + fg] = packed;
}

// ---------------------------------------------------------------------------
// MFMA projection (fp16) + LN + ReLU (+ fused readout on last layer).
// 2 node-tiles per wave (32 nodes): each B-fragment loaded ONCE, used for 2
// MFMAs -> B traffic and per-output issue halved. XCD-aligned grid.
// ---------------------------------------------------------------------------
__global__ __launch_bounds__(256) void k_proj_mfma(u16* __restrict__ xh,
        const u16* __restrict__ aggh, const u16* __restrict__ wt,
        const float* __restrict__ ln_g, const float* __restrict__ ln_b, int l,
        int last, const float* __restrict__ W_out, const float* __restrict__ b_out,
        float* __restrict__ out){
    int lane = threadIdx.x & 63;
    int wq   = threadIdx.x >> 6;
    int k8   = blockIdx.x & 7;
    int b    = ((k8 & 3) << 1) | (k8 >> 2);   // inverse of xcd(b)=(b>>1)+4*(b&1)
    int tile = blockIdx.x >> 3;
    int n0   = tile*128 + wq*32;              // 32 nodes for this wave
    int mrow = lane & 15;
    int kq   = lane >> 4;
    int nA = n0 + mrow;       if(nA >= Nk) nA = Nk - 1;
    int nB = n0 + 16 + mrow;  if(nB >= Nk) nB = Nk - 1;

    f32x4 accA[4], accB[4];
    #pragma unroll
    for(int jt = 0; jt < 4; ++jt){
        accA[jt] = (f32x4){0.f,0.f,0.f,0.f};
        accB[jt] = (f32x4){0.f,0.f,0.f,0.f};
    }

    const u16* wl = wt + (size_t)l*16384;

    #pragma unroll
    for(int mt = 0; mt < 4; ++mt){
        const u16* basep = (mt == 0)
            ? xh   + (size_t)b*Nk*64
            : aggh + (((size_t)(mt-1)*Bk + b)*Nk)*64;
        const u16* arowA = basep + (size_t)nA*64;
        const u16* arowB = basep + (size_t)nB*64;
        #pragma unroll
        for(int kc = 0; kc < 2; ++kc){
            f16x8 aA = *(const f16x8*)(arowA + kc*32 + kq*8);
            f16x8 aB = *(const f16x8*)(arowB + kc*32 + kq*8);
            #pragma unroll
            for(int jt = 0; jt < 4; ++jt){
                size_t wi = ((size_t)((mt*2 + kc)*4 + jt)*64 + lane)*8;
                f16x8 bfrag = *(const f16x8*)(wl + wi);
                accA[jt] = __builtin_amdgcn_mfma_f32_16x16x32_f16(aA, bfrag, accA[jt], 0, 0, 0);
                accB[jt] = __builtin_amdgcn_mfma_f32_16x16x32_f16(aB, bfrag, accB[jt], 0, 0, 0);
            }
        }
    }

    float gv[4], bv[4], wo[4];
    #pragma unroll
    for(int jt = 0; jt < 4; ++jt){
        int f = jt*16 + mrow;
        gv[jt] = ln_g[l*64 + f];
        bv[jt] = ln_b[l*64 + f];
        wo[jt] = W_out[f];
    }
    float bo = b_out[0];
    u16* xdst = xh + (size_t)b*Nk*64;

    #pragma unroll
    for(int half = 0; half < 2; ++half){
        f32x4* acc = half ? accB : accA;
        int nbase = n0 + half*16;
        #pragma unroll
        for(int v = 0; v < 4; ++v){
            float s1 = acc[0][v] + acc[1][v] + acc[2][v] + acc[3][v];
            float s2 = acc[0][v]*acc[0][v] + acc[1][v]*acc[1][v]
                     + acc[2][v]*acc[2][v] + acc[3][v]*acc[3][v];
            #pragma unroll
            for(int off = 1; off <= 8; off <<= 1){
                s1 += __shfl_xor(s1, off);
                s2 += __shfl_xor(s2, off);
            }
            float mu  = s1 * 0.015625f;
            float var = s2 * 0.015625f - mu*mu;
            float rstd = rsqrtf(var + 1e-3f);
            int node = nbase + kq*4 + v;
            if(!last){
                if(node < Nk){
                    #pragma unroll
                    for(int jt = 0; jt < 4; ++jt){
                        float o = (acc[jt][v] - mu) * rstd * gv[jt] + bv[jt];
                        xdst[(size_t)node*64 + jt*16 + mrow] = f2h_bits(fmaxf(o, 0.f));
                    }
                }
            }else{
                float s3 = 0.f;
                #pragma unroll
                for(int jt = 0; jt < 4; ++jt){
                    float o = (acc[jt][v] - mu) * rstd * gv[jt] + bv[jt];
                    s3 += fmaxf(o, 0.f) * wo[jt];
                }
                #pragma unroll
                for(int off = 1; off <= 8; off <<= 1)
                    s3 += __shfl_xor(s3, off);
                if(mrow == 0 && node < Nk)
                    out[(size_t)b*Nk + node] = s3 + bo;
            }
        }
    }
}

// ---------------------------------------------------------------------------
extern "C" void kernel_launch(void* const* d_in, const int* in_sizes, int n_in,
                              void* d_out, int out_size, void* d_ws, size_t ws_size,
                              hipStream_t stream){
    const float* ctl        = (const float*)d_in[0];
    const float* dt         = (const float*)d_in[1];
    const float* drug_fp    = (const float*)d_in[2];
    const float* edge_w     = (const float*)d_in[3];
    const int*   cell_idx   = (const int*)  d_in[4];
    const int*   edge_index = (const int*)  d_in[5];
    const float* W_se       = (const float*)d_in[6];
    const float* b_se       = (const float*)d_in[7];
    const float* cell_emb   = (const float*)d_in[8];
    const float* W_f1       = (const float*)d_in[9];
    const float* b_f1       = (const float*)d_in[10];
    const float* W_f2       = (const float*)d_in[11];
    const float* b_f2       = (const float*)d_in[12];
    const float* Wself      = (const float*)d_in[13];
    const float* Wrel       = (const float*)d_in[14];
    const float* ln_g       = (const float*)d_in[15];
    const float* ln_b       = (const float*)d_in[16];
    const float* W_out      = (const float*)d_in[17];
    const float* b_out      = (const float*)d_in[18];
    float* out = (float*)d_out;

    char* p = (char*)d_ws;
    auto alloc = [&](size_t bytes)->char*{
        char* r = p; p += (bytes + 255) & ~(size_t)255; return r;
    };
    int*   deg    = (int*)  alloc((size_t)Rk*Nk*4);
    int*   cursor = (int*)  alloc((size_t)Rk*Nk*4);
    int*   offs   = (int*)  alloc((size_t)Rk*(Nk+1)*4);
    int2*  epack  = (int2*) alloc((size_t)Rk*Ek*8);
    float* hid    = (float*)alloc((size_t)Bk*64*4);
    float* g1p    = (float*)alloc((size_t)Bk*64*4);
    float* beta   = (float*)alloc((size_t)Bk*64*4);
    u16*   xh     = (u16*)  alloc((size_t)Bk*Nk*64*2);
    u16*   aggh   = (u16*)  alloc((size_t)3*Bk*Nk*64*2);
    u16*   wt     = (u16*)  alloc((size_t)Lk*16384*2);

    // weight prep + deg zeroing (65536 threads covers wt AND deg)
    k_wprep<<<(Lk*4*2*4*64*8 + 255)/256, 256, 0, stream>>>(Wself, Wrel, wt, deg);

    // fused prep pipeline (4-edge vectorized count/fill)
    k_count_film1<<<CNT4B + Bk*64, 256, 0, stream>>>(edge_index, deg, drug_fp, W_f1, b_f1, hid);
    k_scan_film2<<<3 + Bk, 1024, 0, stream>>>(deg, offs, cursor, hid, W_f2, b_f2, g1p, beta);
    k_fill_init<<<CNT4B + INITB, 256, 0, stream>>>(edge_index, edge_w, cursor, epack,
                                                   ctl, dt, cell_idx, W_se, b_se, cell_emb,
                                                   g1p, beta, xh);

    // layers
    const int ntile = (Nk + 127)/128;          // 79
    for(int l = 0; l < Lk; ++l){
        k_agg<<<4*7500, 256, 0, stream>>>(xh, offs, epack, aggh);
        k_proj_mfma<<<ntile*8, 256, 0, stream>>>(
            xh, aggh, wt, ln_g, ln_b, l,
            (l == Lk-1) ? 1 : 0, W_out, b_out, out);
    }
}

// Round 3
// 403.011 us; speedup vs baseline: 1.4525x; 1.0246x over previous
//
#include <hip/hip_runtime.h>
#include <hip/hip_bf16.h>
#include <math.h>

#define Bk 8
#define Nk 10000
#define Hk 64
#define Lk 4
#define Rk 3
#define Ek 200000
#define FPk 2048

#define C4 (Rk*Ek/4)              /* 150000 edge-quads */
#define CNT4B ((C4 + 255)/256)    /* 586 count/fill blocks (4 edges/thread) */
#define INITB 2048

typedef unsigned short u16;
typedef unsigned int   u32;
typedef _Float16 f16;
typedef __attribute__((ext_vector_type(2))) _Float16 f16x2;
typedef __attribute__((ext_vector_type(8))) _Float16 f16x8;
typedef __attribute__((ext_vector_type(4))) float f32x4;

__device__ __forceinline__ f16x2 as_h2(u32 u){
    union{u32 i; f16x2 h;} v; v.i = u; return v.h;
}
__device__ __forceinline__ u32 as_u32(f16x2 h){
    union{u32 i; f16x2 h;} v; v.h = h; return v.i;
}
__device__ __forceinline__ u16 f2h_bits(float f){
    union{f16 h; u16 u;} v; v.h = (f16)f; return v.u;
}

// ---------------------------------------------------------------------------
// Weight prep (fp16, MFMA B layout) + deg zeroing. Grid covers 65536 threads.
// ---------------------------------------------------------------------------
__global__ void k_wprep(const float* __restrict__ Wself, const float* __restrict__ Wrel,
                        u16* __restrict__ wt, int* __restrict__ deg){
    int idx = blockIdx.x*256 + threadIdx.x;
    if(idx < Rk*Nk) deg[idx] = 0;
    if(idx >= Lk*4*2*4*64*8) return;
    int j    = idx & 7;
    int lane = (idx >> 3) & 63;
    int jt   = (idx >> 9) & 3;
    int kc   = (idx >> 11) & 1;
    int mt   = (idx >> 12) & 3;
    int l    = idx >> 14;
    int k    = kc*32 + (lane >> 4)*8 + j;
    int col  = jt*16 + (lane & 15);
    float w = (mt == 0) ? Wself[(l*64 + k)*64 + col]
                        : Wrel[((l*3 + (mt-1))*64 + k)*64 + col];
    wt[idx] = f2h_bits(w);
}

// ---------------------------------------------------------------------------
// Fused: deg count (blocks < CNT4B, 4 edges/thread via int4) + FiLM stage 1
// ---------------------------------------------------------------------------
__global__ void k_count_film1(const int* __restrict__ edge_index, int* __restrict__ deg,
                              const float* __restrict__ fp, const float* __restrict__ W1,
                              const float* __restrict__ b1, float* __restrict__ hid){
    __shared__ float red[256];
    if(blockIdx.x < CNT4B){
        int idx = blockIdx.x*256 + threadIdx.x;
        if(idx >= C4) return;
        int g = idx*4;
        int r = g / Ek, e = g % Ek;          // Ek%4==0 -> quad shares r
        int4 d = *(const int4*)&edge_index[r*2*Ek + Ek + e];
        int* dg = deg + r*Nk;
        atomicAdd(&dg[d.x], 1);
        atomicAdd(&dg[d.y], 1);
        atomicAdd(&dg[d.z], 1);
        atomicAdd(&dg[d.w], 1);
    }else{
        int bb = blockIdx.x - CNT4B;         // 0..511
        int b = bb >> 6, h = bb & 63;
        const float* fpb = fp + b*FPk;
        float acc = 0.f;
        for(int k = threadIdx.x; k < FPk; k += 256)
            acc += fpb[k] * W1[k*64 + h];
        red[threadIdx.x] = acc;
        __syncthreads();
        for(int s = 128; s >= 1; s >>= 1){
            if(threadIdx.x < s) red[threadIdx.x] += red[threadIdx.x + s];
            __syncthreads();
        }
        if(threadIdx.x == 0) hid[b*64 + h] = fmaxf(red[0] + b1[h], 0.f);
    }
}

// ---------------------------------------------------------------------------
// Fused: CSR scan (blocks 0..2, 1024 thr) + FiLM stage 2 (blocks 3..10)
// ---------------------------------------------------------------------------
__global__ void k_scan_film2(const int* __restrict__ deg, int* __restrict__ offs,
                             int* __restrict__ cursor,
                             const float* __restrict__ hid, const float* __restrict__ W2,
                             const float* __restrict__ b2,
                             float* __restrict__ g1p, float* __restrict__ beta){
    __shared__ int s[1024];
    if(blockIdx.x < 3){
        int r = blockIdx.x;
        int t = threadIdx.x;
        int base_i = t*10;
        int local[10];
        int sum = 0;
        if(base_i < Nk){
            #pragma unroll
            for(int k = 0; k < 10; ++k){ local[k] = deg[r*Nk + base_i + k]; sum += local[k]; }
        }
        s[t] = sum;
        __syncthreads();
        for(int d = 1; d < 1024; d <<= 1){
            int v = (t >= d) ? s[t-d] : 0;
            __syncthreads();
            s[t] += v;
            __syncthreads();
        }
        if(base_i < Nk){
            int excl = s[t] - sum;
            #pragma unroll
            for(int k = 0; k < 10; ++k){
                offs[r*(Nk+1) + base_i + k] = excl;
                cursor[r*Nk + base_i + k]   = excl;
                excl += local[k];
            }
        }
        if(t == 1023) offs[r*(Nk+1) + Nk] = s[1023];
    }else{
        int b = blockIdx.x - 3;                // 0..7
        int j = threadIdx.x;
        if(j < 128){
            float acc = b2[j];
            for(int k = 0; k < 64; ++k)
                acc += hid[b*64 + k] * W2[k*128 + j];
            if(j < 64) g1p[b*64 + j] = 1.f + tanhf(acc);
            else       beta[b*64 + j - 64] = acc;
        }
    }
}

// ---------------------------------------------------------------------------
// Fused: CSR fill (blocks < CNT4B, 4 edges/thread) + x0 init (8 feats/thread,
// 16B stores) on INITB blocks after.
// ---------------------------------------------------------------------------
__global__ void k_fill_init(const int* __restrict__ edge_index, const float* __restrict__ edge_weight,
                            int* __restrict__ cursor, int2* __restrict__ epack,
                            const float* __restrict__ ctl, const float* __restrict__ dt,
                            const int* __restrict__ cell_idx,
                            const float* __restrict__ W_se, const float* __restrict__ b_se,
                            const float* __restrict__ cell_emb,
                            const float* __restrict__ g1p, const float* __restrict__ beta,
                            u16* __restrict__ xh){
    if(blockIdx.x < CNT4B){
        int idx = blockIdx.x*256 + threadIdx.x;
        if(idx >= C4) return;
        int g = idx*4;
        int r = g / Ek, e = g % Ek;
        int4   s4 = *(const int4*)  &edge_index [r*2*Ek + e];
        int4   d4 = *(const int4*)  &edge_index [r*2*Ek + Ek + e];
        float4 w4 = *(const float4*)&edge_weight[r*Ek + e];
        int2* epr = epack + (size_t)r*Ek;
        int*  cur = cursor + r*Nk;
        int pos;
        f16 h;
        pos = atomicAdd(&cur[d4.x], 1); h = (f16)w4.x;
        epr[pos] = make_int2(s4.x << 7, (int)as_u32((f16x2){h, h}));
        pos = atomicAdd(&cur[d4.y], 1); h = (f16)w4.y;
        epr[pos] = make_int2(s4.y << 7, (int)as_u32((f16x2){h, h}));
        pos = atomicAdd(&cur[d4.z], 1); h = (f16)w4.z;
        epr[pos] = make_int2(s4.z << 7, (int)as_u32((f16x2){h, h}));
        pos = atomicAdd(&cur[d4.w], 1); h = (f16)w4.w;
        epr[pos] = make_int2(s4.w << 7, (int)as_u32((f16x2){h, h}));
    }else{
        const size_t total8 = (size_t)Bk*Nk*8;       // 640000 feat-octets
        size_t start = (size_t)(blockIdx.x - CNT4B)*256 + threadIdx.x;
        for(size_t i8 = start; i8 < total8; i8 += (size_t)INITB*256){
            int hq = (int)(i8 & 7);                  // feat octet 0..7
            size_t bn = i8 >> 3;
            int b = (int)(bn / Nk);
            float c = ctl[bn], d = dt[bn];
            int ci = cell_idx[b];
            u32 pk[4];
            #pragma unroll
            for(int j = 0; j < 8; j += 2){
                int h0 = hq*8 + j, h1 = h0 + 1;
                float w0 = W_se[h0], s0 = b_se[h0];
                float w1 = W_se[h1], s1 = b_se[h1];
                float v0 = fmaxf(c*w0 + s0, 0.f) + fmaxf(d*w0 + s0, 0.f)
                         + cell_emb[ci*64 + h0];
                float v1 = fmaxf(c*w1 + s1, 0.f) + fmaxf(d*w1 + s1, 0.f)
                         + cell_emb[ci*64 + h1];
                v0 = v0 * g1p[b*64 + h0] + beta[b*64 + h0];
                v1 = v1 * g1p[b*64 + h1] + beta[b*64 + h1];
                pk[j >> 1] = (u32)f2h_bits(v0) | ((u32)f2h_bits(v1) << 16);
            }
            *(int4*)&xh[i8*8] = make_int4(pk[0], pk[1], pk[2], pk[3]);
        }
    }
}

// ---------------------------------------------------------------------------
// agg (fp16), R3 restructure: wave = one (r,dst) x 2 batches, lanes split as
// 4 edge-groups x 16 slots (2 batch x 8 feat-quads). Each group processes its
// own edge with ONE dwordx4 (16B) load covering 8 feats -> VMEM instrs/edge
// drop 4x (1 -> 0.25) at identical line count (4/edge), testing whether the
// ~12.7 TB/s plateau is an outstanding-INSTRUCTION window limit (lines in
// flight per vmcnt slot x4) vs an MSHR/line limit (then neutral + VALUBusy
// halves). VALU/edge also ~halves (4 pk_fma per 16 lanes vs per 64).
// Cross-group reduce in f32 at list end; eg==0 lanes store dwordx4.
// bpair=blockIdx&3 -> per-XCD 2.56MB x-slice (L2-hit) unchanged.
// ---------------------------------------------------------------------------
__global__ __launch_bounds__(256) void k_agg(const u16* __restrict__ xh,
                      const int* __restrict__ offs, const int2* __restrict__ epack,
                      u16* __restrict__ aggh){
    __shared__ int2 stash[4][64];
    int bpair = blockIdx.x & 3;
    int grp   = blockIdx.x >> 2;                   // 0..7499
    int wq    = threadIdx.x >> 6;
    int wid   = grp*4 + wq;                        // 0..29999 = (r,dst)
    int lane  = threadIdx.x & 63;
    int eg    = lane >> 4;                         // edge group 0..3
    int slot  = lane & 15;
    int bl    = slot >> 3;                         // local batch 0/1
    int fq    = slot & 7;                          // feat quad (8 fp16 = 16B)
    int r = wid / Nk, dst = wid % Nk;
    int o0 = offs[r*(Nk+1) + dst], o1 = offs[r*(Nk+1) + dst + 1];
    const int2* ep = epack + (size_t)r*Ek;
    const char* xb = (const char*)xh + (size_t)(bpair*2 + bl)*Nk*128 + fq*16;

    f16x2 a0 = (f16x2){0,0}, a1 = (f16x2){0,0};
    f16x2 a2 = (f16x2){0,0}, a3 = (f16x2){0,0};
    int2* st = stash[wq];
    for(int base = o0; base < o1; base += 64){
        int j = base + lane;
        if(j < o1) st[lane] = ep[j];
        int cnt = min(o1 - base, 64);
        int t = 0;
        for(; t + 8 <= cnt; t += 8){
            int2 q0 = st[t + eg];
            int2 q1 = st[t + 4 + eg];
            int4 d0 = *(const int4*)(xb + q0.x);
            int4 d1 = *(const int4*)(xb + q1.x);
            f16x2 w0 = as_h2((u32)q0.y), w1 = as_h2((u32)q1.y);
            a0 += as_h2((u32)d0.x)*w0; a1 += as_h2((u32)d0.y)*w0;
            a2 += as_h2((u32)d0.z)*w0; a3 += as_h2((u32)d0.w)*w0;
            a0 += as_h2((u32)d1.x)*w1; a1 += as_h2((u32)d1.y)*w1;
            a2 += as_h2((u32)d1.z)*w1; a3 += as_h2((u32)d1.w)*w1;
        }
        for(; t < cnt; t += 4){
            int idx = t + eg;
            int2 q = st[min(idx, cnt - 1)];
            u32 wbits = (idx < cnt) ? (u32)q.y : 0u;
            int4 d = *(const int4*)(xb + q.x);
            f16x2 w = as_h2(wbits);
            a0 += as_h2((u32)d.x)*w; a1 += as_h2((u32)d.y)*w;
            a2 += as_h2((u32)d.z)*w; a3 += as_h2((u32)d.w)*w;
        }
    }
    // cross-edge-group reduce (lanes eg=0..3 hold partials of same slot)
    float f0 = (float)a0.x, f1 = (float)a0.y, f2 = (float)a1.x, f3 = (float)a1.y;
    float f4 = (float)a2.x, f5 = (float)a2.y, f6 = (float)a3.x, f7 = (float)a3.y;
    f0 += __shfl_xor(f0, 16); f0 += __shfl_xor(f0, 32);
    f1 += __shfl_xor(f1, 16); f1 += __shfl_xor(f1, 32);
    f2 += __shfl_xor(f2, 16); f2 += __shfl_xor(f2, 32);
    f3 += __shfl_xor(f3, 16); f3 += __shfl_xor(f3, 32);
    f4 += __shfl_xor(f4, 16); f4 += __shfl_xor(f4, 32);
    f5 += __shfl_xor(f5, 16); f5 += __shfl_xor(f5, 32);
    f6 += __shfl_xor(f6, 16); f6 += __shfl_xor(f6, 32);
    f7 += __shfl_xor(f7, 16); f7 += __shfl_xor(f7, 32);
    if(eg == 0){
        u32 p0 = (u32)f2h_bits(f0) | ((u32)f2h_bits(f1) << 16);
        u32 p1 = (u32)f2h_bits(f2) | ((u32)f2h_bits(f3) << 16);
        u32 p2 = (u32)f2h_bits(f4) | ((u32)f2h_bits(f5) << 16);
        u32 p3 = (u32)f2h_bits(f6) | ((u32)f2h_bits(f7) << 16);
        u16* dp = aggh + (((size_t)r*Bk + (bpair*2 + bl))*Nk + dst)*64 + fq*8;
        *(int4*)dp = make_int4((int)p0, (int)p1, (int)p2, (int)p3);
    }
}

// ---------------------------------------------------------------------------
// MFMA projection (fp16) + LN + ReLU (+ fused readout on last layer).
// 2 node-tiles per wave (32 nodes): each B-fragment loaded ONCE, used for 2
// MFMAs -> B traffic and per-output issue halved. XCD-aligned grid.
// ---------------------------------------------------------------------------
__global__ __launch_bounds__(256) void k_proj_mfma(u16* __restrict__ xh,
        const u16* __restrict__ aggh, const u16* __restrict__ wt,
        const float* __restrict__ ln_g, const float* __restrict__ ln_b, int l,
        int last, const float* __restrict__ W_out, const float* __restrict__ b_out,
        float* __restrict__ out){
    int lane = threadIdx.x & 63;
    int wq   = threadIdx.x >> 6;
    int k8   = blockIdx.x & 7;
    int b    = ((k8 & 3) << 1) | (k8 >> 2);   // inverse of xcd(b)=(b>>1)+4*(b&1)
    int tile = blockIdx.x >> 3;
    int n0   = tile*128 + wq*32;              // 32 nodes for this wave
    int mrow = lane & 15;
    int kq   = lane >> 4;
    int nA = n0 + mrow;       if(nA >= Nk) nA = Nk - 1;
    int nB = n0 + 16 + mrow;  if(nB >= Nk) nB = Nk - 1;

    f32x4 accA[4], accB[4];
    #pragma unroll
    for(int jt = 0; jt < 4; ++jt){
        accA[jt] = (f32x4){0.f,0.f,0.f,0.f};
        accB[jt] = (f32x4){0.f,0.f,0.f,0.f};
    }

    const u16* wl = wt + (size_t)l*16384;

    #pragma unroll
    for(int mt = 0; mt < 4; ++mt){
        const u16* basep = (mt == 0)
            ? xh   + (size_t)b*Nk*64
            : aggh + (((size_t)(mt-1)*Bk + b)*Nk)*64;
        const u16* arowA = basep + (size_t)nA*64;
        const u16* arowB = basep + (size_t)nB*64;
        #pragma unroll
        for(int kc = 0; kc < 2; ++kc){
            f16x8 aA = *(const f16x8*)(arowA + kc*32 + kq*8);
            f16x8 aB = *(const f16x8*)(arowB + kc*32 + kq*8);
            #pragma unroll
            for(int jt = 0; jt < 4; ++jt){
                size_t wi = ((size_t)((mt*2 + kc)*4 + jt)*64 + lane)*8;
                f16x8 bfrag = *(const f16x8*)(wl + wi);
                accA[jt] = __builtin_amdgcn_mfma_f32_16x16x32_f16(aA, bfrag, accA[jt], 0, 0, 0);
                accB[jt] = __builtin_amdgcn_mfma_f32_16x16x32_f16(aB, bfrag, accB[jt], 0, 0, 0);
            }
        }
    }

    float gv[4], bv[4], wo[4];
    #pragma unroll
    for(int jt = 0; jt < 4; ++jt){
        int f = jt*16 + mrow;
        gv[jt] = ln_g[l*64 + f];
        bv[jt] = ln_b[l*64 + f];
        wo[jt] = W_out[f];
    }
    float bo = b_out[0];
    u16* xdst = xh + (size_t)b*Nk*64;

    #pragma unroll
    for(int half = 0; half < 2; ++half){
        f32x4* acc = half ? accB : accA;
        int nbase = n0 + half*16;
        #pragma unroll
        for(int v = 0; v < 4; ++v){
            float s1 = acc[0][v] + acc[1][v] + acc[2][v] + acc[3][v];
            float s2 = acc[0][v]*acc[0][v] + acc[1][v]*acc[1][v]
                     + acc[2][v]*acc[2][v] + acc[3][v]*acc[3][v];
            #pragma unroll
            for(int off = 1; off <= 8; off <<= 1){
                s1 += __shfl_xor(s1, off);
                s2 += __shfl_xor(s2, off);
            }
            float mu  = s1 * 0.015625f;
            float var = s2 * 0.015625f - mu*mu;
            float rstd = rsqrtf(var + 1e-3f);
            int node = nbase + kq*4 + v;
            if(!last){
                if(node < Nk){
                    #pragma unroll
                    for(int jt = 0; jt < 4; ++jt){
                        float o = (acc[jt][v] - mu) * rstd * gv[jt] + bv[jt];
                        xdst[(size_t)node*64 + jt*16 + mrow] = f2h_bits(fmaxf(o, 0.f));
                    }
                }
            }else{
                float s3 = 0.f;
                #pragma unroll
                for(int jt = 0; jt < 4; ++jt){
                    float o = (acc[jt][v] - mu) * rstd * gv[jt] + bv[jt];
                    s3 += fmaxf(o, 0.f) * wo[jt];
                }
                #pragma unroll
                for(int off = 1; off <= 8; off <<= 1)
                    s3 += __shfl_xor(s3, off);
                if(mrow == 0 && node < Nk)
                    out[(size_t)b*Nk + node] = s3 + bo;
            }
        }
    }
}

// ---------------------------------------------------------------------------
extern "C" void kernel_launch(void* const* d_in, const int* in_sizes, int n_in,
                              void* d_out, int out_size, void* d_ws, size_t ws_size,
                              hipStream_t stream){
    const float* ctl        = (const float*)d_in[0];
    const float* dt         = (const float*)d_in[1];
    const float* drug_fp    = (const float*)d_in[2];
    const float* edge_w     = (const float*)d_in[3];
    const int*   cell_idx   = (const int*)  d_in[4];
    const int*   edge_index = (const int*)  d_in[5];
    const float* W_se       = (const float*)d_in[6];
    const float* b_se       = (const float*)d_in[7];
    const float* cell_emb   = (const float*)d_in[8];
    const float* W_f1       = (const float*)d_in[9];
    const float* b_f1       = (const float*)d_in[10];
    const float* W_f2       = (const float*)d_in[11];
    const float* b_f2       = (const float*)d_in[12];
    const float* Wself      = (const float*)d_in[13];
    const float* Wrel       = (const float*)d_in[14];
    const float* ln_g       = (const float*)d_in[15];
    const float* ln_b       = (const float*)d_in[16];
    const float* W_out      = (const float*)d_in[17];
    const float* b_out      = (const float*)d_in[18];
    float* out = (float*)d_out;

    char* p = (char*)d_ws;
    auto alloc = [&](size_t bytes)->char*{
        char* r = p; p += (bytes + 255) & ~(size_t)255; return r;
    };
    int*   deg    = (int*)  alloc((size_t)Rk*Nk*4);
    int*   cursor = (int*)  alloc((size_t)Rk*Nk*4);
    int*   offs   = (int*)  alloc((size_t)Rk*(Nk+1)*4);
    int2*  epack  = (int2*) alloc((size_t)Rk*Ek*8);
    float* hid    = (float*)alloc((size_t)Bk*64*4);
    float* g1p    = (float*)alloc((size_t)Bk*64*4);
    float* beta   = (float*)alloc((size_t)Bk*64*4);
    u16*   xh     = (u16*)  alloc((size_t)Bk*Nk*64*2);
    u16*   aggh   = (u16*)  alloc((size_t)3*Bk*Nk*64*2);
    u16*   wt     = (u16*)  alloc((size_t)Lk*16384*2);

    // weight prep + deg zeroing (65536 threads covers wt AND deg)
    k_wprep<<<(Lk*4*2*4*64*8 + 255)/256, 256, 0, stream>>>(Wself, Wrel, wt, deg);

    // fused prep pipeline (4-edge vectorized count/fill)
    k_count_film1<<<CNT4B + Bk*64, 256, 0, stream>>>(edge_index, deg, drug_fp, W_f1, b_f1, hid);
    k_scan_film2<<<3 + Bk, 1024, 0, stream>>>(deg, offs, cursor, hid, W_f2, b_f2, g1p, beta);
    k_fill_init<<<CNT4B + INITB, 256, 0, stream>>>(edge_index, edge_w, cursor, epack,
                                                   ctl, dt, cell_idx, W_se, b_se, cell_emb,
                                                   g1p, beta, xh);

    // layers
    const int ntile = (Nk + 127)/128;          // 79
    for(int l = 0; l < Lk; ++l){
        k_agg<<<4*7500, 256, 0, stream>>>(xh, offs, epack, aggh);
        k_proj_mfma<<<ntile*8, 256, 0, stream>>>(
            xh, aggh, wt, ln_g, ln_b, l,
            (l == Lk-1) ? 1 : 0, W_out, b_out, out);
    }
}

// Round 4
// 374.443 us; speedup vs baseline: 1.5634x; 1.0763x over previous
//
#include <hip/hip_runtime.h>
#include <hip/hip_bf16.h>
#include <math.h>

#define Bk 8
#define Nk 10000
#define Hk 64
#define Lk 4
#define Rk 3
#define Ek 200000
#define FPk 2048

#define C4 (Rk*Ek/4)              /* 150000 edge-quads */
#define CNT4B ((C4 + 255)/256)    /* 586 edge-fill blocks (4 edges/thread) */
#define INITB 2048                /* 8 batches x 256 x0-init blocks */

typedef unsigned short u16;
typedef unsigned int   u32;
typedef _Float16 f16;
typedef __attribute__((ext_vector_type(2))) _Float16 f16x2;
typedef __attribute__((ext_vector_type(8))) _Float16 f16x8;
typedef __attribute__((ext_vector_type(4))) float f32x4;

__device__ __forceinline__ f16x2 as_h2(u32 u){
    union{u32 i; f16x2 h;} v; v.i = u; return v.h;
}
__device__ __forceinline__ u32 as_u32(f16x2 h){
    union{u32 i; f16x2 h;} v; v.h = h; return v.i;
}
__device__ __forceinline__ u16 f2h_bits(float f){
    union{f16 h; u16 u;} v; v.h = (f16)f; return v.u;
}

// ---------------------------------------------------------------------------
// k_prep0: weight prep (fp16, MFMA B layout) + deg zeroing (blocks 0..255)
//          + FiLM stage 1 (blocks 256..767).
// ---------------------------------------------------------------------------
__global__ void k_prep0(const float* __restrict__ Wself, const float* __restrict__ Wrel,
                        u16* __restrict__ wt, int* __restrict__ deg,
                        const float* __restrict__ fp, const float* __restrict__ W1,
                        const float* __restrict__ b1, float* __restrict__ hid){
    __shared__ float red[256];
    if(blockIdx.x < 256){
        int idx = blockIdx.x*256 + threadIdx.x;      // 0..65535
        if(idx < Rk*Nk) deg[idx] = 0;
        int j    = idx & 7;
        int lane = (idx >> 3) & 63;
        int jt   = (idx >> 9) & 3;
        int kc   = (idx >> 11) & 1;
        int mt   = (idx >> 12) & 3;
        int l    = idx >> 14;
        int k    = kc*32 + (lane >> 4)*8 + j;
        int col  = jt*16 + (lane & 15);
        float w = (mt == 0) ? Wself[(l*64 + k)*64 + col]
                            : Wrel[((l*3 + (mt-1))*64 + k)*64 + col];
        wt[idx] = f2h_bits(w);
    }else{
        int bb = blockIdx.x - 256;                   // 0..511
        int b = bb >> 6, h = bb & 63;
        const float* fpb = fp + b*FPk;
        float acc = 0.f;
        for(int k = threadIdx.x; k < FPk; k += 256)
            acc += fpb[k] * W1[k*64 + h];
        red[threadIdx.x] = acc;
        __syncthreads();
        for(int s = 128; s >= 1; s >>= 1){
            if(threadIdx.x < s) red[threadIdx.x] += red[threadIdx.x + s];
            __syncthreads();
        }
        if(threadIdx.x == 0) hid[b*64 + h] = fmaxf(red[0] + b1[h], 0.f);
    }
}

// ---------------------------------------------------------------------------
// k_fill2: ELL edge fill (blocks < CNT4B, 4 edges/thread; atomicAdd(deg)
// returns the slot -> count pass and CSR scan ELIMINATED) + x0 init (INITB
// blocks after; each block serves ONE batch and recomputes FiLM-2 for that
// batch into LDS -> film2 kernel boundary eliminated).
// ELL width 64: deg ~ Poisson(20), P(any of 30k bins >= 64) ~ 1e-10; fill
// guards pos<64, agg clamps cnt<=64 (no OOB either way).
// ---------------------------------------------------------------------------
__global__ void k_fill2(const int* __restrict__ edge_index, const float* __restrict__ edge_weight,
                        int* __restrict__ deg, int2* __restrict__ epack,
                        const float* __restrict__ ctl, const float* __restrict__ dt,
                        const int* __restrict__ cell_idx,
                        const float* __restrict__ W_se, const float* __restrict__ b_se,
                        const float* __restrict__ cell_emb,
                        const float* __restrict__ hid, const float* __restrict__ W2,
                        const float* __restrict__ b2,
                        u16* __restrict__ xh){
    __shared__ float g1l[64], btl[64];
    if(blockIdx.x < CNT4B){
        int idx = blockIdx.x*256 + threadIdx.x;
        if(idx >= C4) return;
        int g = idx*4;
        int r = g / Ek, e = g % Ek;                 // Ek%4==0 -> quad shares r
        int4   s4 = *(const int4*)  &edge_index [r*2*Ek + e];
        int4   d4 = *(const int4*)  &edge_index [r*2*Ek + Ek + e];
        float4 w4 = *(const float4*)&edge_weight[r*Ek + e];
        int* dg = deg + r*Nk;
        size_t ebase = (size_t)r*Nk;
        int pos; f16 h;
        pos = atomicAdd(&dg[d4.x], 1); h = (f16)w4.x;
        if(pos < 64) epack[((ebase + d4.x) << 6) + pos] = make_int2(s4.x << 7, (int)as_u32((f16x2){h, h}));
        pos = atomicAdd(&dg[d4.y], 1); h = (f16)w4.y;
        if(pos < 64) epack[((ebase + d4.y) << 6) + pos] = make_int2(s4.y << 7, (int)as_u32((f16x2){h, h}));
        pos = atomicAdd(&dg[d4.z], 1); h = (f16)w4.z;
        if(pos < 64) epack[((ebase + d4.z) << 6) + pos] = make_int2(s4.z << 7, (int)as_u32((f16x2){h, h}));
        pos = atomicAdd(&dg[d4.w], 1); h = (f16)w4.w;
        if(pos < 64) epack[((ebase + d4.w) << 6) + pos] = make_int2(s4.w << 7, (int)as_u32((f16x2){h, h}));
    }else{
        int bb  = blockIdx.x - CNT4B;               // 0..2047
        int b   = bb >> 8;                          // batch
        int blk = bb & 255;
        int t = threadIdx.x;
        // FiLM-2 for this batch (64x128 MACs, trivial)
        if(t < 128){
            float acc = b2[t];
            #pragma unroll 8
            for(int k = 0; k < 64; ++k)
                acc += hid[b*64 + k] * W2[k*128 + t];
            if(t < 64) g1l[t] = 1.f + tanhf(acc);
            else       btl[t - 64] = acc;
        }
        __syncthreads();
        int ci = cell_idx[b];
        const int per_b = Nk*8;                     // 80000 feat-octets
        for(int o = blk*256 + t; o < per_b; o += 256*256){
            int hq = o & 7;
            int n  = o >> 3;
            float c = ctl[b*Nk + n], d = dt[b*Nk + n];
            u32 pk[4];
            #pragma unroll
            for(int j = 0; j < 8; j += 2){
                int h0 = hq*8 + j, h1 = h0 + 1;
                float w0 = W_se[h0], s0 = b_se[h0];
                float w1 = W_se[h1], s1 = b_se[h1];
                float v0 = fmaxf(c*w0 + s0, 0.f) + fmaxf(d*w0 + s0, 0.f)
                         + cell_emb[ci*64 + h0];
                float v1 = fmaxf(c*w1 + s1, 0.f) + fmaxf(d*w1 + s1, 0.f)
                         + cell_emb[ci*64 + h1];
                v0 = v0 * g1l[h0] + btl[h0];
                v1 = v1 * g1l[h1] + btl[h1];
                pk[j >> 1] = (u32)f2h_bits(v0) | ((u32)f2h_bits(v1) << 16);
            }
            *(int4*)&xh[(((size_t)b*Nk + n)*64) + hq*8] = make_int4(pk[0], pk[1], pk[2], pk[3]);
        }
    }
}

// ---------------------------------------------------------------------------
// agg (fp16): R0-proven body (best measured: 47.4us), ELL addressing.
// wave = one (r,dst) x 2 batches (lane>>5) x 32 feat-dwords (lane&31).
// cnt<=64 -> single stash pass, no offs loads, no base loop.
// bpair=blockIdx&3 -> per-XCD 2.56MB x-slice (L2-hit). At the measured L2
// random-line floor (~13 TB/s; R0/R2/R3 structure-invariant).
// ---------------------------------------------------------------------------
__global__ __launch_bounds__(256) void k_agg(const u16* __restrict__ xh,
                      const int* __restrict__ deg, const int2* __restrict__ epack,
                      u16* __restrict__ aggh){
    __shared__ int2 stash[4][64];
    int bpair = blockIdx.x & 3;
    int grp   = blockIdx.x >> 2;                   // 0..7499
    int wq    = threadIdx.x >> 6;
    int wid   = grp*4 + wq;                        // 0..29999 = (r,dst)
    int lane  = threadIdx.x & 63;
    int fg    = lane & 31;                         // feat dword: feats fg*2, fg*2+1
    int bl    = lane >> 5;                         // local batch 0/1
    int b     = bpair*2 + bl;
    int r = wid / Nk, dst = wid % Nk;
    int cnt = deg[wid]; if(cnt > 64) cnt = 64;
    const int2* ep = epack + ((size_t)wid << 6);
    const char* xb = (const char*)xh + (size_t)b*Nk*128 + fg*4;

    f16x2 A = (f16x2){0,0}, C = (f16x2){0,0};      // 2 accumulation chains
    int2* st = stash[wq];
    if(lane < cnt) st[lane] = ep[lane];
    int t = 0;
    for(; t + 8 <= cnt; t += 8){
        int4 q01 = *(const int4*)&st[t];
        int4 q23 = *(const int4*)&st[t+2];
        int4 q45 = *(const int4*)&st[t+4];
        int4 q67 = *(const int4*)&st[t+6];
        u32 u0 = *(const u32*)(xb + q01.x);
        u32 u1 = *(const u32*)(xb + q01.z);
        u32 u2 = *(const u32*)(xb + q23.x);
        u32 u3 = *(const u32*)(xb + q23.z);
        u32 u4 = *(const u32*)(xb + q45.x);
        u32 u5 = *(const u32*)(xb + q45.z);
        u32 u6 = *(const u32*)(xb + q67.x);
        u32 u7 = *(const u32*)(xb + q67.z);
        A += as_h2(u0)*as_h2(q01.y); C += as_h2(u1)*as_h2(q01.w);
        A += as_h2(u2)*as_h2(q23.y); C += as_h2(u3)*as_h2(q23.w);
        A += as_h2(u4)*as_h2(q45.y); C += as_h2(u5)*as_h2(q45.w);
        A += as_h2(u6)*as_h2(q67.y); C += as_h2(u7)*as_h2(q67.w);
    }
    for(; t + 2 <= cnt; t += 2){
        int4 q01 = *(const int4*)&st[t];
        u32 u0 = *(const u32*)(xb + q01.x);
        u32 u1 = *(const u32*)(xb + q01.z);
        A += as_h2(u0)*as_h2(q01.y); C += as_h2(u1)*as_h2(q01.w);
    }
    if(t < cnt){
        int2 p = st[t];
        u32 u = *(const u32*)(xb + p.x);
        A += as_h2(u)*as_h2(p.y);
    }
    float a0 = (float)A.x + (float)C.x;
    float a1 = (float)A.y + (float)C.y;
    u32 packed = (u32)f2h_bits(a0) | ((u32)f2h_bits(a1) << 16);
    ((u32*)aggh)[(((size_t)r*Bk + b)*Nk + dst)*32 + fg] = packed;
}

// ---------------------------------------------------------------------------
// MFMA projection (fp16) + LN + ReLU (+ fused readout on last layer).
// wt tile staged in LDS once per block (32KB, shared by 4 waves): B-fragment
// loads go from ~200cy L2 hits to conflict-free ds_read_b128 -> attacks the
// latency-bound critical path. 2 node-tiles per wave (32 nodes). XCD-aligned.
// ---------------------------------------------------------------------------
__global__ __launch_bounds__(256) void k_proj_mfma(u16* __restrict__ xh,
        const u16* __restrict__ aggh, const u16* __restrict__ wt,
        const float* __restrict__ ln_g, const float* __restrict__ ln_b, int l,
        int last, const float* __restrict__ W_out, const float* __restrict__ b_out,
        float* __restrict__ out){
    __shared__ u16 wls[16384];
    const u16* wl = wt + (size_t)l*16384;
    for(int i = threadIdx.x; i < 2048; i += 256)
        *(int4*)&wls[i*8] = *(const int4*)&wl[i*8];
    __syncthreads();

    int lane = threadIdx.x & 63;
    int wq   = threadIdx.x >> 6;
    int k8   = blockIdx.x & 7;
    int b    = ((k8 & 3) << 1) | (k8 >> 2);   // inverse of xcd(b)=(b>>1)+4*(b&1)
    int tile = blockIdx.x >> 3;
    int n0   = tile*128 + wq*32;              // 32 nodes for this wave
    int mrow = lane & 15;
    int kq   = lane >> 4;
    int nA = n0 + mrow;       if(nA >= Nk) nA = Nk - 1;
    int nB = n0 + 16 + mrow;  if(nB >= Nk) nB = Nk - 1;

    f32x4 accA[4], accB[4];
    #pragma unroll
    for(int jt = 0; jt < 4; ++jt){
        accA[jt] = (f32x4){0.f,0.f,0.f,0.f};
        accB[jt] = (f32x4){0.f,0.f,0.f,0.f};
    }

    #pragma unroll
    for(int mt = 0; mt < 4; ++mt){
        const u16* basep = (mt == 0)
            ? xh   + (size_t)b*Nk*64
            : aggh + (((size_t)(mt-1)*Bk + b)*Nk)*64;
        const u16* arowA = basep + (size_t)nA*64;
        const u16* arowB = basep + (size_t)nB*64;
        #pragma unroll
        for(int kc = 0; kc < 2; ++kc){
            f16x8 aA = *(const f16x8*)(arowA + kc*32 + kq*8);
            f16x8 aB = *(const f16x8*)(arowB + kc*32 + kq*8);
            #pragma unroll
            for(int jt = 0; jt < 4; ++jt){
                f16x8 bfrag = *(const f16x8*)(wls + ((size_t)((mt*2 + kc)*4 + jt)*64 + lane)*8);
                accA[jt] = __builtin_amdgcn_mfma_f32_16x16x32_f16(aA, bfrag, accA[jt], 0, 0, 0);
                accB[jt] = __builtin_amdgcn_mfma_f32_16x16x32_f16(aB, bfrag, accB[jt], 0, 0, 0);
            }
        }
    }

    float gv[4], bv[4], wo[4];
    #pragma unroll
    for(int jt = 0; jt < 4; ++jt){
        int f = jt*16 + mrow;
        gv[jt] = ln_g[l*64 + f];
        bv[jt] = ln_b[l*64 + f];
        wo[jt] = W_out[f];
    }
    float bo = b_out[0];
    u16* xdst = xh + (size_t)b*Nk*64;

    #pragma unroll
    for(int half = 0; half < 2; ++half){
        f32x4* acc = half ? accB : accA;
        int nbase = n0 + half*16;
        #pragma unroll
        for(int v = 0; v < 4; ++v){
            float s1 = acc[0][v] + acc[1][v] + acc[2][v] + acc[3][v];
            float s2 = acc[0][v]*acc[0][v] + acc[1][v]*acc[1][v]
                     + acc[2][v]*acc[2][v] + acc[3][v]*acc[3][v];
            #pragma unroll
            for(int off = 1; off <= 8; off <<= 1){
                s1 += __shfl_xor(s1, off);
                s2 += __shfl_xor(s2, off);
            }
            float mu  = s1 * 0.015625f;
            float var = s2 * 0.015625f - mu*mu;
            float rstd = rsqrtf(var + 1e-3f);
            int node = nbase + kq*4 + v;
            if(!last){
                if(node < Nk){
                    #pragma unroll
                    for(int jt = 0; jt < 4; ++jt){
                        float o = (acc[jt][v] - mu) * rstd * gv[jt] + bv[jt];
                        xdst[(size_t)node*64 + jt*16 + mrow] = f2h_bits(fmaxf(o, 0.f));
                    }
                }
            }else{
                float s3 = 0.f;
                #pragma unroll
                for(int jt = 0; jt < 4; ++jt){
                    float o = (acc[jt][v] - mu) * rstd * gv[jt] + bv[jt];
                    s3 += fmaxf(o, 0.f) * wo[jt];
                }
                #pragma unroll
                for(int off = 1; off <= 8; off <<= 1)
                    s3 += __shfl_xor(s3, off);
                if(mrow == 0 && node < Nk)
                    out[(size_t)b*Nk + node] = s3 + bo;
            }
        }
    }
}

// ---------------------------------------------------------------------------
extern "C" void kernel_launch(void* const* d_in, const int* in_sizes, int n_in,
                              void* d_out, int out_size, void* d_ws, size_t ws_size,
                              hipStream_t stream){
    const float* ctl        = (const float*)d_in[0];
    const float* dt         = (const float*)d_in[1];
    const float* drug_fp    = (const float*)d_in[2];
    const float* edge_w     = (const float*)d_in[3];
    const int*   cell_idx   = (const int*)  d_in[4];
    const int*   edge_index = (const int*)  d_in[5];
    const float* W_se       = (const float*)d_in[6];
    const float* b_se       = (const float*)d_in[7];
    const float* cell_emb   = (const float*)d_in[8];
    const float* W_f1       = (const float*)d_in[9];
    const float* b_f1       = (const float*)d_in[10];
    const float* W_f2       = (const float*)d_in[11];
    const float* b_f2       = (const float*)d_in[12];
    const float* Wself      = (const float*)d_in[13];
    const float* Wrel       = (const float*)d_in[14];
    const float* ln_g       = (const float*)d_in[15];
    const float* ln_b       = (const float*)d_in[16];
    const float* W_out      = (const float*)d_in[17];
    const float* b_out      = (const float*)d_in[18];
    float* out = (float*)d_out;

    char* p = (char*)d_ws;
    auto alloc = [&](size_t bytes)->char*{
        char* r = p; p += (bytes + 255) & ~(size_t)255; return r;
    };
    int*   deg    = (int*)  alloc((size_t)Rk*Nk*4);
    int2*  epack  = (int2*) alloc((size_t)Rk*Nk*64*8);   /* ELL, 15.36MB */
    float* hid    = (float*)alloc((size_t)Bk*64*4);
    u16*   xh     = (u16*)  alloc((size_t)Bk*Nk*64*2);
    u16*   aggh   = (u16*)  alloc((size_t)3*Bk*Nk*64*2);
    u16*   wt     = (u16*)  alloc((size_t)Lk*16384*2);

    // prep: 2 kernels (was 4). k_prep0 = weights + deg zero + FiLM-1.
    k_prep0<<<256 + Bk*64, 256, 0, stream>>>(Wself, Wrel, wt, deg,
                                             drug_fp, W_f1, b_f1, hid);
    // k_fill2 = ELL edge fill (atomic slot) + x0 init (per-block FiLM-2).
    k_fill2<<<CNT4B + INITB, 256, 0, stream>>>(edge_index, edge_w, deg, epack,
                                               ctl, dt, cell_idx, W_se, b_se, cell_emb,
                                               hid, W_f2, b_f2, xh);

    // layers
    const int ntile = (Nk + 127)/128;          // 79
    for(int l = 0; l < Lk; ++l){
        k_agg<<<4*7500, 256, 0, stream>>>(xh, deg, epack, aggh);
        k_proj_mfma<<<ntile*8, 256, 0, stream>>>(
            xh, aggh, wt, ln_g, ln_b, l,
            (l == Lk-1) ? 1 : 0, W_out, b_out, out);
    }
}

// Round 5
// 362.583 us; speedup vs baseline: 1.6145x; 1.0327x over previous
//
#include <hip/hip_runtime.h>
#include <hip/hip_bf16.h>
#include <math.h>

#define Bk 8
#define Nk 10000
#define Hk 64
#define Lk 4
#define Rk 3
#define Ek 200000
#define FPk 2048

#define C4 (Rk*Ek/4)              /* 150000 edge-quads */
#define CNT4B ((C4 + 255)/256)    /* 586 edge-fill blocks (4 edges/thread) */
#define INITB 2048                /* 8 batches x 256 x0-init blocks */
#define DEGW  (Rk*Nk*16)          /* padded deg: one counter per 64B line */

typedef unsigned short u16;
typedef unsigned int   u32;
typedef _Float16 f16;
typedef __attribute__((ext_vector_type(2))) _Float16 f16x2;
typedef __attribute__((ext_vector_type(8))) _Float16 f16x8;
typedef __attribute__((ext_vector_type(4))) float f32x4;

__device__ __forceinline__ f16x2 as_h2(u32 u){
    union{u32 i; f16x2 h;} v; v.i = u; return v.h;
}
__device__ __forceinline__ u32 as_u32(f16x2 h){
    union{u32 i; f16x2 h;} v; v.h = h; return v.i;
}
__device__ __forceinline__ u16 f2h_bits(float f){
    union{f16 h; u16 u;} v; v.h = (f16)f; return v.u;
}

// ---------------------------------------------------------------------------
// k_prep0: weight prep (fp16, MFMA B layout) + padded-deg zeroing
//          (blocks 0..255) + FiLM stage 1 (blocks 256..767).
// ---------------------------------------------------------------------------
__global__ void k_prep0(const float* __restrict__ Wself, const float* __restrict__ Wrel,
                        u16* __restrict__ wt, int* __restrict__ deg,
                        const float* __restrict__ fp, const float* __restrict__ W1,
                        const float* __restrict__ b1, float* __restrict__ hid){
    __shared__ float red[256];
    if(blockIdx.x < 256){
        int idx = blockIdx.x*256 + threadIdx.x;      // 0..65535
        if(idx < DEGW/8){                            // zero 8 ints each (60000 thr)
            *(int4*)&deg[idx*8]     = make_int4(0,0,0,0);
            *(int4*)&deg[idx*8 + 4] = make_int4(0,0,0,0);
        }
        int j    = idx & 7;
        int lane = (idx >> 3) & 63;
        int jt   = (idx >> 9) & 3;
        int kc   = (idx >> 11) & 1;
        int mt   = (idx >> 12) & 3;
        int l    = idx >> 14;
        int k    = kc*32 + (lane >> 4)*8 + j;
        int col  = jt*16 + (lane & 15);
        float w = (mt == 0) ? Wself[(l*64 + k)*64 + col]
                            : Wrel[((l*3 + (mt-1))*64 + k)*64 + col];
        wt[idx] = f2h_bits(w);
    }else{
        int bb = blockIdx.x - 256;                   // 0..511
        int b = bb >> 6, h = bb & 63;
        const float* fpb = fp + b*FPk;
        float acc = 0.f;
        for(int k = threadIdx.x; k < FPk; k += 256)
            acc += fpb[k] * W1[k*64 + h];
        red[threadIdx.x] = acc;
        __syncthreads();
        for(int s = 128; s >= 1; s >>= 1){
            if(threadIdx.x < s) red[threadIdx.x] += red[threadIdx.x + s];
            __syncthreads();
        }
        if(threadIdx.x == 0) hid[b*64 + h] = fmaxf(red[0] + b1[h], 0.f);
    }
}

// ---------------------------------------------------------------------------
// k_efill: ELL edge fill, 4 edges/thread. atomicAdd on LINE-PADDED counters
// (one per 64B line) -> kills cross-XCD line ping-pong (R4 theory: ~320
// same-line RMWs x ~200cy migration = the 52us floor). Entries packed to 4B
// ((w16<<16)|src) -> scatter-write line footprint halves.
// ELL width 64: deg ~ Poisson(20), P(overflow anywhere) ~ 1e-10; guarded.
// ---------------------------------------------------------------------------
__global__ void k_efill(const int* __restrict__ edge_index, const float* __restrict__ edge_weight,
                        int* __restrict__ deg, u32* __restrict__ epack){
    int idx = blockIdx.x*256 + threadIdx.x;
    if(idx >= C4) return;
    int g = idx*4;
    int r = g / Ek, e = g % Ek;                 // Ek%4==0 -> quad shares r
    int4   s4 = *(const int4*)  &edge_index [r*2*Ek + e];
    int4   d4 = *(const int4*)  &edge_index [r*2*Ek + Ek + e];
    float4 w4 = *(const float4*)&edge_weight[r*Ek + e];
    int* dg = deg + (size_t)r*Nk*16;
    size_t ebase = (size_t)r*Nk;
    int pos;
    pos = atomicAdd(&dg[(size_t)d4.x*16], 1);
    if(pos < 64) epack[((ebase + d4.x) << 6) + pos] = ((u32)f2h_bits(w4.x) << 16) | (u32)s4.x;
    pos = atomicAdd(&dg[(size_t)d4.y*16], 1);
    if(pos < 64) epack[((ebase + d4.y) << 6) + pos] = ((u32)f2h_bits(w4.y) << 16) | (u32)s4.y;
    pos = atomicAdd(&dg[(size_t)d4.z*16], 1);
    if(pos < 64) epack[((ebase + d4.z) << 6) + pos] = ((u32)f2h_bits(w4.z) << 16) | (u32)s4.z;
    pos = atomicAdd(&dg[(size_t)d4.w*16], 1);
    if(pos < 64) epack[((ebase + d4.w) << 6) + pos] = ((u32)f2h_bits(w4.w) << 16) | (u32)s4.w;
}

// ---------------------------------------------------------------------------
// k_xinit: x0 init. Each block serves ONE batch (blockIdx>>8) and recomputes
// FiLM-2 for that batch into LDS (64x128 MACs, trivial). 16B coalesced stores.
// ---------------------------------------------------------------------------
__global__ void k_xinit(const float* __restrict__ ctl, const float* __restrict__ dt,
                        const int* __restrict__ cell_idx,
                        const float* __restrict__ W_se, const float* __restrict__ b_se,
                        const float* __restrict__ cell_emb,
                        const float* __restrict__ hid, const float* __restrict__ W2,
                        const float* __restrict__ b2,
                        u16* __restrict__ xh){
    __shared__ float g1l[64], btl[64];
    int b   = blockIdx.x >> 8;                  // batch
    int blk = blockIdx.x & 255;
    int t = threadIdx.x;
    if(t < 128){
        float acc = b2[t];
        #pragma unroll 8
        for(int k = 0; k < 64; ++k)
            acc += hid[b*64 + k] * W2[k*128 + t];
        if(t < 64) g1l[t] = 1.f + tanhf(acc);
        else       btl[t - 64] = acc;
    }
    __syncthreads();
    int ci = cell_idx[b];
    const int per_b = Nk*8;                     // 80000 feat-octets
    for(int o = blk*256 + t; o < per_b; o += 256*256){
        int hq = o & 7;
        int n  = o >> 3;
        float c = ctl[b*Nk + n], d = dt[b*Nk + n];
        u32 pk[4];
        #pragma unroll
        for(int j = 0; j < 8; j += 2){
            int h0 = hq*8 + j, h1 = h0 + 1;
            float w0 = W_se[h0], s0 = b_se[h0];
            float w1 = W_se[h1], s1 = b_se[h1];
            float v0 = fmaxf(c*w0 + s0, 0.f) + fmaxf(d*w0 + s0, 0.f)
                     + cell_emb[ci*64 + h0];
            float v1 = fmaxf(c*w1 + s1, 0.f) + fmaxf(d*w1 + s1, 0.f)
                     + cell_emb[ci*64 + h1];
            v0 = v0 * g1l[h0] + btl[h0];
            v1 = v1 * g1l[h1] + btl[h1];
            pk[j >> 1] = (u32)f2h_bits(v0) | ((u32)f2h_bits(v1) << 16);
        }
        *(int4*)&xh[(((size_t)b*Nk + n)*64) + hq*8] = make_int4(pk[0], pk[1], pk[2], pk[3]);
    }
}

// ---------------------------------------------------------------------------
// agg (fp16): R0-proven hot loop, ELL addressing, 4B entries unpacked ONCE at
// stash fill (off = src<<7, w2 = {w,w}) -> inner loop byte-identical to R0.
// wave = one (r,dst) x 2 batches (lane>>5) x 32 feat-dwords (lane&31).
// bpair=blockIdx&3 -> per-XCD 2.56MB x-slice (L2-hit). At the measured L2
// random-line floor (~13 TB/s; R0/R2/R3 structure-invariant).
// ---------------------------------------------------------------------------
__global__ __launch_bounds__(256) void k_agg(const u16* __restrict__ xh,
                      const int* __restrict__ deg, const u32* __restrict__ epack,
                      u16* __restrict__ aggh){
    __shared__ int2 stash[4][64];
    int bpair = blockIdx.x & 3;
    int grp   = blockIdx.x >> 2;                   // 0..7499
    int wq    = threadIdx.x >> 6;
    int wid   = grp*4 + wq;                        // 0..29999 = (r,dst)
    int lane  = threadIdx.x & 63;
    int fg    = lane & 31;                         // feat dword: feats fg*2, fg*2+1
    int bl    = lane >> 5;                         // local batch 0/1
    int b     = bpair*2 + bl;
    int r = wid / Nk, dst = wid % Nk;
    int cnt = deg[(size_t)wid*16]; if(cnt > 64) cnt = 64;
    const u32* ep = epack + ((size_t)wid << 6);
    const char* xb = (const char*)xh + (size_t)b*Nk*128 + fg*4;

    f16x2 A = (f16x2){0,0}, C = (f16x2){0,0};      // 2 accumulation chains
    int2* st = stash[wq];
    if(lane < cnt){
        u32 e = ep[lane];
        st[lane] = make_int2((int)((e & 0xFFFFu) << 7),
                             (int)((e >> 16) | (e & 0xFFFF0000u)));
    }
    int t = 0;
    for(; t + 8 <= cnt; t += 8){
        int4 q01 = *(const int4*)&st[t];
        int4 q23 = *(const int4*)&st[t+2];
        int4 q45 = *(const int4*)&st[t+4];
        int4 q67 = *(const int4*)&st[t+6];
        u32 u0 = *(const u32*)(xb + q01.x);
        u32 u1 = *(const u32*)(xb + q01.z);
        u32 u2 = *(const u32*)(xb + q23.x);
        u32 u3 = *(const u32*)(xb + q23.z);
        u32 u4 = *(const u32*)(xb + q45.x);
        u32 u5 = *(const u32*)(xb + q45.z);
        u32 u6 = *(const u32*)(xb + q67.x);
        u32 u7 = *(const u32*)(xb + q67.z);
        A += as_h2(u0)*as_h2(q01.y); C += as_h2(u1)*as_h2(q01.w);
        A += as_h2(u2)*as_h2(q23.y); C += as_h2(u3)*as_h2(q23.w);
        A += as_h2(u4)*as_h2(q45.y); C += as_h2(u5)*as_h2(q45.w);
        A += as_h2(u6)*as_h2(q67.y); C += as_h2(u7)*as_h2(q67.w);
    }
    for(; t + 2 <= cnt; t += 2){
        int4 q01 = *(const int4*)&st[t];
        u32 u0 = *(const u32*)(xb + q01.x);
        u32 u1 = *(const u32*)(xb + q01.z);
        A += as_h2(u0)*as_h2(q01.y); C += as_h2(u1)*as_h2(q01.w);
    }
    if(t < cnt){
        int2 p = st[t];
        u32 u = *(const u32*)(xb + p.x);
        A += as_h2(u)*as_h2(p.y);
    }
    float a0 = (float)A.x + (float)C.x;
    float a1 = (float)A.y + (float)C.y;
    u32 packed = (u32)f2h_bits(a0) | ((u32)f2h_bits(a1) << 16);
    ((u32*)aggh)[(((size_t)r*Bk + b)*Nk + dst)*32 + fg] = packed;
}

// ---------------------------------------------------------------------------
// MFMA projection (fp16) + LN + ReLU (+ fused readout on last layer).
// wt tile staged in LDS once per block (32KB, shared by 4 waves). 2 node-
// tiles per wave (32 nodes). XCD-aligned grid.
// ---------------------------------------------------------------------------
__global__ __launch_bounds__(256) void k_proj_mfma(u16* __restrict__ xh,
        const u16* __restrict__ aggh, const u16* __restrict__ wt,
        const float* __restrict__ ln_g, const float* __restrict__ ln_b, int l,
        int last, const float* __restrict__ W_out, const float* __restrict__ b_out,
        float* __restrict__ out){
    __shared__ u16 wls[16384];
    const u16* wl = wt + (size_t)l*16384;
    for(int i = threadIdx.x; i < 2048; i += 256)
        *(int4*)&wls[i*8] = *(const int4*)&wl[i*8];
    __syncthreads();

    int lane = threadIdx.x & 63;
    int wq   = threadIdx.x >> 6;
    int k8   = blockIdx.x & 7;
    int b    = ((k8 & 3) << 1) | (k8 >> 2);   // inverse of xcd(b)=(b>>1)+4*(b&1)
    int tile = blockIdx.x >> 3;
    int n0   = tile*128 + wq*32;              // 32 nodes for this wave
    int mrow = lane & 15;
    int kq   = lane >> 4;
    int nA = n0 + mrow;       if(nA >= Nk) nA = Nk - 1;
    int nB = n0 + 16 + mrow;  if(nB >= Nk) nB = Nk - 1;

    f32x4 accA[4], accB[4];
    #pragma unroll
    for(int jt = 0; jt < 4; ++jt){
        accA[jt] = (f32x4){0.f,0.f,0.f,0.f};
        accB[jt] = (f32x4){0.f,0.f,0.f,0.f};
    }

    #pragma unroll
    for(int mt = 0; mt < 4; ++mt){
        const u16* basep = (mt == 0)
            ? xh   + (size_t)b*Nk*64
            : aggh + (((size_t)(mt-1)*Bk + b)*Nk)*64;
        const u16* arowA = basep + (size_t)nA*64;
        const u16* arowB = basep + (size_t)nB*64;
        #pragma unroll
        for(int kc = 0; kc < 2; ++kc){
            f16x8 aA = *(const f16x8*)(arowA + kc*32 + kq*8);
            f16x8 aB = *(const f16x8*)(arowB + kc*32 + kq*8);
            #pragma unroll
            for(int jt = 0; jt < 4; ++jt){
                f16x8 bfrag = *(const f16x8*)(wls + ((size_t)((mt*2 + kc)*4 + jt)*64 + lane)*8);
                accA[jt] = __builtin_amdgcn_mfma_f32_16x16x32_f16(aA, bfrag, accA[jt], 0, 0, 0);
                accB[jt] = __builtin_amdgcn_mfma_f32_16x16x32_f16(aB, bfrag, accB[jt], 0, 0, 0);
            }
        }
    }

    float gv[4], bv[4], wo[4];
    #pragma unroll
    for(int jt = 0; jt < 4; ++jt){
        int f = jt*16 + mrow;
        gv[jt] = ln_g[l*64 + f];
        bv[jt] = ln_b[l*64 + f];
        wo[jt] = W_out[f];
    }
    float bo = b_out[0];
    u16* xdst = xh + (size_t)b*Nk*64;

    #pragma unroll
    for(int half = 0; half < 2; ++half){
        f32x4* acc = half ? accB : accA;
        int nbase = n0 + half*16;
        #pragma unroll
        for(int v = 0; v < 4; ++v){
            float s1 = acc[0][v] + acc[1][v] + acc[2][v] + acc[3][v];
            float s2 = acc[0][v]*acc[0][v] + acc[1][v]*acc[1][v]
                     + acc[2][v]*acc[2][v] + acc[3][v]*acc[3][v];
            #pragma unroll
            for(int off = 1; off <= 8; off <<= 1){
                s1 += __shfl_xor(s1, off);
                s2 += __shfl_xor(s2, off);
            }
            float mu  = s1 * 0.015625f;
            float var = s2 * 0.015625f - mu*mu;
            float rstd = rsqrtf(var + 1e-3f);
            int node = nbase + kq*4 + v;
            if(!last){
                if(node < Nk){
                    #pragma unroll
                    for(int jt = 0; jt < 4; ++jt){
                        float o = (acc[jt][v] - mu) * rstd * gv[jt] + bv[jt];
                        xdst[(size_t)node*64 + jt*16 + mrow] = f2h_bits(fmaxf(o, 0.f));
                    }
                }
            }else{
                float s3 = 0.f;
                #pragma unroll
                for(int jt = 0; jt < 4; ++jt){
                    float o = (acc[jt][v] - mu) * rstd * gv[jt] + bv[jt];
                    s3 += fmaxf(o, 0.f) * wo[jt];
                }
                #pragma unroll
                for(int off = 1; off <= 8; off <<= 1)
                    s3 += __shfl_xor(s3, off);
                if(mrow == 0 && node < Nk)
                    out[(size_t)b*Nk + node] = s3 + bo;
            }
        }
    }
}

// ---------------------------------------------------------------------------
extern "C" void kernel_launch(void* const* d_in, const int* in_sizes, int n_in,
                              void* d_out, int out_size, void* d_ws, size_t ws_size,
                              hipStream_t stream){
    const float* ctl        = (const float*)d_in[0];
    const float* dt         = (const float*)d_in[1];
    const float* drug_fp    = (const float*)d_in[2];
    const float* edge_w     = (const float*)d_in[3];
    const int*   cell_idx   = (const int*)  d_in[4];
    const int*   edge_index = (const int*)  d_in[5];
    const float* W_se       = (const float*)d_in[6];
    const float* b_se       = (const float*)d_in[7];
    const float* cell_emb   = (const float*)d_in[8];
    const float* W_f1       = (const float*)d_in[9];
    const float* b_f1       = (const float*)d_in[10];
    const float* W_f2       = (const float*)d_in[11];
    const float* b_f2       = (const float*)d_in[12];
    const float* Wself      = (const float*)d_in[13];
    const float* Wrel       = (const float*)d_in[14];
    const float* ln_g       = (const float*)d_in[15];
    const float* ln_b       = (const float*)d_in[16];
    const float* W_out      = (const float*)d_in[17];
    const float* b_out      = (const float*)d_in[18];
    float* out = (float*)d_out;

    char* p = (char*)d_ws;
    auto alloc = [&](size_t bytes)->char*{
        char* r = p; p += (bytes + 255) & ~(size_t)255; return r;
    };
    int*   deg    = (int*)  alloc((size_t)DEGW*4);       /* padded, 1.92MB */
    u32*   epack  = (u32*)  alloc((size_t)Rk*Nk*64*4);   /* ELL 4B, 7.68MB */
    float* hid    = (float*)alloc((size_t)Bk*64*4);
    u16*   xh     = (u16*)  alloc((size_t)Bk*Nk*64*2);
    u16*   aggh   = (u16*)  alloc((size_t)3*Bk*Nk*64*2);
    u16*   wt     = (u16*)  alloc((size_t)Lk*16384*2);

    // prep: weights + padded-deg zero + FiLM-1
    k_prep0<<<256 + Bk*64, 256, 0, stream>>>(Wself, Wrel, wt, deg,
                                             drug_fp, W_f1, b_f1, hid);
    // ELL edge fill (line-padded atomic slot assignment)
    k_efill<<<CNT4B, 256, 0, stream>>>(edge_index, edge_w, deg, epack);
    // x0 init (per-block FiLM-2)
    k_xinit<<<INITB, 256, 0, stream>>>(ctl, dt, cell_idx, W_se, b_se, cell_emb,
                                       hid, W_f2, b_f2, xh);

    // layers
    const int ntile = (Nk + 127)/128;          // 79
    for(int l = 0; l < Lk; ++l){
        k_agg<<<4*7500, 256, 0, stream>>>(xh, deg, epack, aggh);
        k_proj_mfma<<<ntile*8, 256, 0, stream>>>(
            xh, aggh, wt, ln_g, ln_b, l,
            (l == Lk-1) ? 1 : 0, W_out, b_out, out);
    }
}